// Round 19
// baseline (531.310 us; speedup 1.0000x reference)
//
#include <hip/hip_runtime.h>
#include <math.h>

#define NB 256
#define NT 1024
#define NUNF 6
#define TBS 128
#define CHK 8
#define NTJMAX 12
#define L2E 1.44269504088896340736f
#define PI_F 3.14159265358979324f

typedef const float* fp;

extern "C" __device__ float __ocml_exp2_f32(float);
__device__ __forceinline__ float frcp(float x) { return __builtin_amdgcn_rcpf(x); }
__device__ __forceinline__ float ex2(float x) { return __ocml_exp2_f32(x); }
__device__ __forceinline__ float sgm(float a, float b, float v) { return frcp(1.f + ex2(fmaf(a, v, b))); }

struct Tables {
    int ngroups, npos, nchunks, ntraj;
    int grp_start[21];
    int ord[20];
    int pos[20];
    int aff[20];
    int need_traj[20];
    int traj_slot[20];
    int ch_ps[20], ch_pe[20], ch_gs[20], ch_ge[20];
    int ncp[20], nip[20], ngp[20];
    float cmt[20], cn0[20], cd0[20];
    float icmt[12];
    int   cp_pre[20][8];          // traj SLOT of the pre unit
    float cp_a[20][8], cp_b[20][8], cp_w[20][8], cp_e[20][8];
    int   ip_i[20][12];
    float ip_a[20][12], ip_b[20][12], ip_w[20][12], ip_e[20][12];
    int   gp_pre[20][6];
    float gp_a[20][6], gp_b[20][6], gp_w[20][6], gp_e[20][6];
};

struct DenseTab {
    int cnt[12];
    float in0[12], id0[12];
    int   pre[12][32];
    float a[12][32], b[12][32], w[12][32], e[12][32];
    int homog, maxcnt;
};

// ws layout
#define WS_DTAB   16384
#define WS_BND    24576
#define WS_MG     32768
#define WS_VST    98304
#define WS_SENSI  131072

// ---------------- K0: wiring analysis, lane-parallel in LDS ----------------
__global__ void build_tables(fp wsyn, fp mu, fp sigma, fp erev, const int* spm,
                             fp sw, fp smu, fp ssg, fp serev, const int* smask,
                             fp cm, fp gleak, fp vleak, fp d1b, Tables* T, DenseTab* D) {
    __shared__ int   spmL[1024], smkL[1024];
    __shared__ float wL[1024], muL[1024], sgL[1024], evL[1024];
    __shared__ float swL[1024], smuL[1024], ssgL[1024], sevL[1024];
    __shared__ float cmL[32], glL[32], vlL[32];
    __shared__ int premaskL[20], ancL[20], rootL[20], depUL[20], keyL[20], posL[20], ordL[20];
    __shared__ int ngpL[20], ntjL[20], slotU[20];
    __shared__ int neededS;
    __shared__ float habs[64];
    __shared__ int cntS[12];
    int tid = threadIdx.x;
    for (int k = tid; k < 1024; k += 64) {
        spmL[k] = spm[k]; wL[k] = wsyn[k]; muL[k] = mu[k]; sgL[k] = sigma[k]; evL[k] = erev[k];
        smkL[k] = smask[k]; swL[k] = sw[k]; smuL[k] = smu[k]; ssgL[k] = ssg[k]; sevL[k] = serev[k];
    }
    if (tid < 32) { cmL[tid] = cm[tid]; glL[tid] = gleak[tid]; vlL[tid] = vleak[tid]; }
    habs[tid] = fmaxf(fabsf(d1b[tid]), fabsf(d1b[tid + 64]));
    __syncthreads();
    if (tid < 20) {
        int pm = 0;
        for (int i = 0; i < 20; ++i) if (spmL[i * 32 + tid]) pm |= 1 << i;
        premaskL[tid] = pm;
        ancL[tid] = pm;
    }
    __syncthreads();
    for (int it = 0; it < 20; ++it) {
        int a = 0;
        if (tid < 20) {
            a = ancL[tid];
            int pm = premaskL[tid];
            for (int i = 0; i < 20; ++i) if ((pm >> i) & 1) a |= ancL[i];
        }
        __syncthreads();
        if (tid < 20) ancL[tid] = a;
        __syncthreads();
    }
    if (tid == 0) neededS = ancL[0] | 1;
    __syncthreads();
    int needed = neededS;
    if (tid < 20) {
        int r = tid;
        if ((needed >> tid) & 1) {
            int aj = ancL[tid];
            for (int i = 0; i < 20; ++i)
                if (i < r && ((needed >> i) & 1) && ((aj >> i) & 1) && ((ancL[i] >> tid) & 1)) r = i;
        }
        rootL[tid] = r;
        depUL[tid] = 0;
    }
    __syncthreads();
    for (int it = 0; it < 21; ++it) {
        int d = 0;
        if (tid < 20 && ((needed >> tid) & 1)) {
            int pm = premaskL[tid], myr = rootL[tid];
            for (int i = 0; i < 20; ++i)
                if (((pm >> i) & 1) && rootL[i] != myr) d = max(d, depUL[i] + 1);
        }
        __syncthreads();
        if (tid < 20 && d > depUL[tid]) depUL[tid] = d;
        __syncthreads();
    }
    if (tid < 20) {
        int key = 0x7FFFFFFF;
        if ((needed >> tid) & 1) {
            int myr = rootL[tid], dg = 0;
            for (int i = 0; i < 20; ++i)
                if (((needed >> i) & 1) && rootL[i] == myr) dg = max(dg, depUL[i]);
            key = dg * 32 + myr;
        }
        keyL[tid] = key;
    }
    __syncthreads();
    if (tid < 20) {
        int mykey = keyL[tid];
        int p = 0;
        for (int k = 0; k < 20; ++k)
            if (keyL[k] < mykey || (keyL[k] == mykey && k < tid)) ++p;
        posL[tid] = p;
        if (p < 20) ordL[p] = tid;
    }
    __syncthreads();
    if (tid < 20) {
        int nt = 0;
        if ((needed >> tid) & 1)
            for (int j = 0; j < 20; ++j)
                if (j != tid && ((needed >> j) & 1) && spmL[tid * 32 + j]) { nt = 1; break; }
        ntjL[tid] = nt;
    }
    __syncthreads();
    if (tid == 0) {
        int s = 0;
        for (int p = 0; p < 20; ++p) { int u = ordL[p]; slotU[u] = s; s += ntjL[u]; }
        T->ntraj = s;
    }
    __syncthreads();
    if (tid < 20) {
        int j = tid, cc = 0, ci = 0, cg = 0;
        T->cmt[j] = cmL[j] * (float)NUNF;
        T->cn0[j] = glL[j] * vlL[j];
        T->cd0[j] = cmL[j] * (float)NUNF + glL[j] + 1e-8f;
        if ((needed >> j) & 1) {
            int myr = rootL[j];
            int mystart = posL[myr];
            for (int i = 0; i < 32; ++i) {
                int p = i * 32 + j;
                if (!spmL[p]) continue;
                float sg = sgL[p];
                float a = -sg * L2E, b = sg * muL[p] * L2E;
                float w = wL[p], e = w * evL[p];
                if (i >= 20) {
                    T->ip_i[j][ci] = i - 20;
                    T->ip_a[j][ci] = a; T->ip_b[j][ci] = b; T->ip_w[j][ci] = w; T->ip_e[j][ci] = e;
                    ++ci;
                } else if (rootL[i] == myr) {
                    T->gp_pre[j][cg] = posL[i] - mystart;
                    T->gp_a[j][cg] = a; T->gp_b[j][cg] = b; T->gp_w[j][cg] = w; T->gp_e[j][cg] = e;
                    ++cg;
                } else {
                    T->cp_pre[j][cc] = slotU[i];
                    T->cp_a[j][cc] = a; T->cp_b[j][cc] = b; T->cp_w[j][cc] = w; T->cp_e[j][cc] = e;
                    ++cc;
                }
            }
        }
        T->ncp[j] = cc; T->nip[j] = ci; T->ngp[j] = cg;
        ngpL[j] = cg;
    }
    if (tid < 12) {
        T->icmt[tid] = cmL[20 + tid] * (float)NUNF;
        int unit = 20 + tid, cnt = 0;
        for (int s = 0; s < 32; ++s) {
            int p = s * 32 + unit;
            if (!smkL[p]) continue;
            float sg = ssgL[p];
            D->pre[tid][cnt] = s;
            D->a[tid][cnt] = -sg * L2E;
            D->b[tid][cnt] = sg * smuL[p] * L2E;
            D->w[tid][cnt] = swL[p];
            D->e[tid][cnt] = swL[p] * sevL[p];
            ++cnt;
        }
        for (int c = cnt; c < 32; ++c) {
            D->pre[tid][c] = 0; D->a[tid][c] = 0.f; D->b[tid][c] = 0.f;
            D->w[tid][c] = 0.f; D->e[tid][c] = 0.f;
        }
        D->cnt[tid] = cnt;
        cntS[tid] = cnt;
        D->in0[tid] = glL[unit] * vlL[unit];
        D->id0[tid] = cmL[unit] * (float)NUNF + glL[unit] + 1e-8f;
    }
    __syncthreads();
    if (tid == 0) {
        int npos = __popc(needed & 0xFFFFF);
        T->npos = npos;
        int ng = 0, prevkey = -1;
        for (int p = 0; p < npos; ++p) {
            int u = ordL[p];
            if (keyL[u] != prevkey) { T->grp_start[ng] = p; ++ng; prevkey = keyL[u]; }
        }
        T->ngroups = ng;
        for (int g = ng; g <= 20; ++g) T->grp_start[g] = npos;
        for (int p = 0; p < 20; ++p) T->ord[p] = (p < npos) ? ordL[p] : 0;
        for (int j = 0; j < 20; ++j) T->pos[j] = posL[j];
        for (int g = 0; g < ng; ++g) {
            int gs = T->grp_start[g], ge = T->grp_start[g + 1], gsz = ge - gs;
            for (int p = gs; p < ge; ++p)
                T->aff[p] = (gsz == 1 && ngpL[ordL[p]] == 0) ? 1 : 0;
        }
        for (int p = npos; p < 20; ++p) T->aff[p] = 0;
        for (int p = 0; p < 20; ++p) {
            int u = ordL[p];
            T->need_traj[p] = ntjL[u];
            T->traj_slot[p] = slotU[u];
        }
        int nchunks = 0, g = 0;
        while (g < ng) {
            int lvl = keyL[ordL[T->grp_start[g]]] / 32;
            int ge = g;
            while (ge < ng && keyL[ordL[T->grp_start[ge]]] / 32 == lvl) ++ge;
            int cs = g;
            while (cs < ge) {
                int ce = cs, acc = 0;
                while (ce < ge) {
                    int gsz = T->grp_start[ce + 1] - T->grp_start[ce];
                    if (acc + gsz > CHK && ce > cs) break;
                    acc += gsz; ++ce;
                    if (acc >= CHK) break;
                }
                T->ch_gs[nchunks] = cs; T->ch_ge[nchunks] = ce;
                T->ch_ps[nchunks] = T->grp_start[cs]; T->ch_pe[nchunks] = T->grp_start[ce];
                ++nchunks;
                cs = ce;
            }
            g = ge;
        }
        T->nchunks = nchunks;
        float hm = 0.f;
        for (int k = 0; k < 64; ++k) hm = fmaxf(hm, habs[k]);
        D->homog = (hm == 0.f) ? 1 : 0;
        int mc = 0;
        for (int k = 0; k < 12; ++k) mc = max(mc, cntS[k]);
        D->maxcnt = mc;
    }
}

// ---------------- K0b: sector boundaries + per-sector 2x32 maps, one kernel ----------------
__global__ void sector_all(fp d1w, fp d2w, fp iw, float* bnd, float2* Mg) {
    __shared__ float ang[256];
    __shared__ float uS[128], vS[128];
    __shared__ int bmaskL[256 * 4];
    __shared__ float W2L[4096];
    int tid = threadIdx.x;
    if (tid < 128) { uS[tid] = d1w[tid]; vS[tid] = d1w[128 + tid]; }
    for (int p = tid; p < 4096; p += 256) W2L[p] = d2w[p];
    __syncthreads();
    {
        int k = tid & 127;
        float al = atan2f(vS[k], uS[k]);
        float bb = (tid < 128) ? al + 1.57079632679489662f : al - 1.57079632679489662f;
        if (bb > PI_F) bb -= 2.f * PI_F;
        if (bb <= -PI_F) bb += 2.f * PI_F;
        ang[tid] = bb;
    }
    __syncthreads();
    for (int k = 2; k <= 256; k <<= 1) {
        for (int j = k >> 1; j > 0; j >>= 1) {
            int ixj = tid ^ j;
            if (ixj > tid) {
                float a0 = ang[tid], a1 = ang[ixj];
                bool up = ((tid & k) == 0);
                if ((a0 > a1) == up) { ang[tid] = a1; ang[ixj] = a0; }
            }
            __syncthreads();
        }
    }
    bnd[tid] = ang[tid];
    float lo = ang[tid];
    float hi = (tid < 255) ? ang[tid + 1] : ang[0] + 2.f * PI_F;
    float tm = 0.5f * (lo + hi);
    float ct = cosf(tm), st = sinf(tm);
    for (int w = 0; w < 4; ++w) {
        int m = 0;
        for (int kk = 0; kk < 32; ++kk) {
            int k = w * 32 + kk;
            if (fmaf(uS[k], ct, vS[k] * st) > 0.f) m |= 1 << kk;
        }
        bmaskL[tid * 4 + w] = m;
    }
    __syncthreads();
    // per-sector collapsed map (thread = sector), prescaled by input_w
    for (int j = 0; j < 32; ++j) {
        float a0 = 0.f, a1 = 0.f;
#pragma unroll
        for (int w = 0; w < 4; ++w) {
            int mm = bmaskL[tid * 4 + w];
            for (int kk = 0; kk < 32; ++kk) {
                if ((mm >> kk) & 1) {
                    int k = w * 32 + kk;
                    float w2 = W2L[k * 32 + j];
                    a0 = fmaf(uS[k], w2, a0);
                    a1 = fmaf(vS[k], w2, a1);
                }
            }
        }
        float iwj = iw[j];
        Mg[tid * 32 + j] = make_float2(a0 * iwj, a1 * iwj);
    }
}

// ---------------- K1b: general fallback dense; early-exits when homog ----------------
__global__ __launch_bounds__(256) void dense_general(
    fp x, fp d1w, fp d1b, fp d2w, fp d2b, fp iw, fp ib,
    const DenseTab* __restrict__ Dg, float2* sensI, int t0, int CT) {
    if (Dg->homog != 0) return;
    __shared__ float W2s[4096];
    __shared__ float W1s[256], b1s[128];
    __shared__ float b2q[32], iwq[32], ibq[32];
    __shared__ float4 tabT[416];
    __shared__ int   preT[416];
    __shared__ int   cntL[12];
    __shared__ float in0L[12], id0L[12];
    __shared__ float hbuf[4][128][20];
    __shared__ float ibuf[4][16][33];
    int tid = threadIdx.x;
    for (int idx = tid; idx < 384; idx += 256) {
        int d = idx >> 5, e = idx & 31;
        int sl = e * 13 + d;
        tabT[sl] = make_float4(Dg->a[d][e], Dg->b[d][e], Dg->w[d][e], Dg->e[d][e]);
        preT[sl] = Dg->pre[d][e];
    }
    if (tid < 12) { cntL[tid] = Dg->cnt[tid]; in0L[tid] = Dg->in0[tid]; id0L[tid] = Dg->id0[tid]; }
    for (int p = tid; p < 4096; p += 256) W2s[p] = d2w[p];
    if (tid < 256) W1s[tid] = d1w[tid];
    if (tid < 128) b1s[tid] = d1b[tid];
    if (tid < 32) { b2q[tid] = d2b[tid]; iwq[tid] = iw[tid]; ibq[tid] = ib[tid]; }
    __syncthreads();
    int wid = tid >> 6, lane = tid & 63;
    float* hb = (float*)hbuf[wid];
    float* ibf = (float*)ibuf[wid];
    const float2* x2 = (const float2*)x;
    int gw = blockIdx.x * 4 + wid;
    int nw = gridDim.x * 4;
    int pass_total = (NB * CT) >> 4;
    int itd1 = lane >> 2, kq = lane & 3;
    int j = lane & 31, half = lane >> 5;
    for (int pass = gw; pass < pass_total; pass += nw) {
        int cg0 = pass * 16;
        {
            int cg = cg0 + itd1;
            int lt = cg >> 8, b = cg & 255;
            float2 xv = x2[b * NT + (t0 + lt)];
#pragma unroll 8
            for (int i = 0; i < 32; ++i) {
                int k = kq + 4 * i;
                float hk = fmaf(xv.y, W1s[128 + k], fmaf(xv.x, W1s[k], b1s[k]));
                hb[k * 20 + itd1] = hk > 0.f ? hk : 0.f;
            }
        }
        __builtin_amdgcn_wave_barrier();
        {
            float a0=0,a1=0,a2=0,a3=0,a4=0,a5=0,a6=0,a7=0;
#pragma unroll 4
            for (int k = 0; k < 128; ++k) {
                float w2 = W2s[k * 32 + j];
                float4 ha = *(const float4*)&hb[k * 20 + half * 8];
                float4 hbv = *(const float4*)&hb[k * 20 + half * 8 + 4];
                a0 = fmaf(ha.x, w2, a0); a1 = fmaf(ha.y, w2, a1);
                a2 = fmaf(ha.z, w2, a2); a3 = fmaf(ha.w, w2, a3);
                a4 = fmaf(hbv.x, w2, a4); a5 = fmaf(hbv.y, w2, a5);
                a6 = fmaf(hbv.z, w2, a6); a7 = fmaf(hbv.w, w2, a7);
            }
            float bb = b2q[j], iww = iwq[j], ibb = ibq[j];
            ibf[(half*8+0)*33+j] = fmaf(a0+bb, iww, ibb);
            ibf[(half*8+1)*33+j] = fmaf(a1+bb, iww, ibb);
            ibf[(half*8+2)*33+j] = fmaf(a2+bb, iww, ibb);
            ibf[(half*8+3)*33+j] = fmaf(a3+bb, iww, ibb);
            ibf[(half*8+4)*33+j] = fmaf(a4+bb, iww, ibb);
            ibf[(half*8+5)*33+j] = fmaf(a5+bb, iww, ibb);
            ibf[(half*8+6)*33+j] = fmaf(a6+bb, iww, ibb);
            ibf[(half*8+7)*33+j] = fmaf(a7+bb, iww, ibb);
        }
        __builtin_amdgcn_wave_barrier();
#pragma unroll
        for (int r = 0; r < 3; ++r) {
            int task = r * 64 + lane;
            int it = task / 12;
            int d = task - it * 12;
            int cnt = cntL[d];
            float wn = in0L[d], wd = id0L[d];
            for (int e = 0; e < cnt; ++e) {
                int sl = e * 13 + d;
                float4 tb = tabT[sl];
                float gq = frcp(1.f + ex2(fmaf(tb.x, ibf[it * 33 + preT[sl]], tb.y)));
                wn = fmaf(tb.w, gq, wn);
                wd = fmaf(tb.z, gq, wd);
            }
            int cg = cg0 + it;
            int lt = cg >> 8, b = cg & 255;
            sensI[(size_t)(b * CT + lt) * 12 + d] = make_float2(wn, wd);
        }
        __builtin_amdgcn_wave_barrier();
    }
}

// ---------------- K2: fused solver: coalesced inline dense (homog) + level-parallel LTC ----------------
__global__ __launch_bounds__(512) void solve(
    fp x, const float2* __restrict__ sensI,
    const Tables* __restrict__ Tg, const DenseTab* __restrict__ Dg,
    const float2* __restrict__ Mg, const float* __restrict__ bndg,
    fp d2b, fp iw, fp ib,
    fp ow, fp ob, float* vstate, int t0, int CT, float* out) {
    __shared__ Tables TL;
    __shared__ float2 iAB[TBS * 12];
    __shared__ float viter[TBS * 13];
    __shared__ float vtraj[NTJMAX * TBS * 7];
    __shared__ float2 pnpd[CHK * TBS * 7];       // aliased as inp scratch during dense phase
    __shared__ float2 comp[CHK * TBS];
    __shared__ float vstart[CHK * TBS];
    __shared__ float gstate[20], istate[12];
    __shared__ float bndL[256];
    __shared__ float4 tabT[416];
    __shared__ int   preT[416];
    __shared__ float cjL[32];
    __shared__ float in0L[12], id0L[12];
    __shared__ int   secS[128];
    __shared__ float x0S[128], x1S[128];
    int tid = threadIdx.x;
    int b = blockIdx.x;
    {
        const int nw = (int)(sizeof(Tables) / 4);
        const int* src = (const int*)Tg;
        int* dst = (int*)&TL;
        for (int k = tid; k < nw; k += 512) dst[k] = src[k];
    }
    int homog = Dg->homog;
    int cntmax = Dg->maxcnt;
    if (homog) {
        for (int idx = tid; idx < 384; idx += 512) {
            int d = idx >> 5, e = idx & 31;
            int sl = e * 13 + d;
            tabT[sl] = make_float4(Dg->a[d][e], Dg->b[d][e], Dg->w[d][e], Dg->e[d][e]);
            preT[sl] = Dg->pre[d][e];
        }
        if (tid < 256) bndL[tid] = bndg[tid];
        if (tid < 32) cjL[tid] = fmaf(d2b[tid], iw[tid], ib[tid]);
        if (tid < 12) { in0L[tid] = Dg->in0[tid]; id0L[tid] = Dg->id0[tid]; }
    }
    __syncthreads();
    if (tid < 20 && tid < TL.npos)
        gstate[tid] = (t0 == 0) ? 0.f : vstate[b * 32 + TL.ord[tid]];
    if (tid < 12)
        istate[tid] = (t0 == 0) ? 0.f : vstate[b * 32 + 20 + tid];
    __syncthreads();
    int ntiles = CT / TBS;
    bool lastChunk = (t0 + CT == NT);
    const float2* x2 = (const float2*)x;
    int nchunks = TL.nchunks;
    for (int tile = 0; tile < ntiles; ++tile) {
        int tbase = tile * TBS;
        if (homog) {
            // ---- phase 1: sector + x per item (128 lanes) ----
            if (tid < 128) {
                float2 xv = x2[(size_t)b * NT + (t0 + tbase + tid)];
                x0S[tid] = xv.x; x1S[tid] = xv.y;
                float th = atan2f(xv.y, xv.x);
                int sec;
                if (th < bndL[0]) sec = 255;
                else {
                    int lo = 0, hi = 255;
#pragma unroll
                    for (int it7 = 0; it7 < 8; ++it7) {
                        int mid = (lo + hi + 1) >> 1;
                        if (bndL[mid] <= th) lo = mid; else hi = mid - 1;
                    }
                    sec = lo;
                }
                secS[tid] = sec;
            }
            __syncthreads();
            // ---- phase 2: inp via COALESCED Mg reads (j lane-consecutive) ----
            float* ibufL = (float*)pnpd;
            {
                int j = tid & 31, grp = tid >> 5;   // 16 groups x 8 items
                float cj = cjL[j];
#pragma unroll
                for (int c = 0; c < 8; ++c) {
                    int item = grp * 8 + c;
                    float2 m = Mg[secS[item] * 32 + j];
                    ibufL[item * 33 + j] = fmaf(x0S[item], m.x, fmaf(x1S[item], m.y, cj));
                }
            }
            __syncthreads();
            // ---- phase 3: gate sums -> iAB (1536 tasks, 3 rounds) ----
#pragma unroll
            for (int rb = 0; rb < 3; ++rb) {
                int task = rb * 512 + tid;
                int item = task / 12;
                int dd = task - item * 12;
                float wn = in0L[dd], wd = id0L[dd];
                for (int e = 0; e < cntmax; ++e) {
                    int sl = e * 13 + dd;
                    float4 tb = tabT[sl];
                    float gq = frcp(1.f + ex2(fmaf(tb.x, ibufL[item * 33 + preT[sl]], tb.y)));
                    wn = fmaf(tb.w, gq, wn);
                    wd = fmaf(tb.z, gq, wd);
                }
                float r = frcp(wd);
                iAB[item * 12 + dd] = make_float2(TL.icmt[dd] * r, wn * r);
            }
        } else {
            for (int w = tid; w < TBS * 16; w += 512) {
                int tt = w >> 4, ii = w & 15;
                if (ii < 12) {
                    float2 s = sensI[(size_t)(b * CT + tbase + tt) * 12 + ii];
                    float r = frcp(s.y);
                    iAB[tt * 12 + ii] = make_float2(TL.icmt[ii] * r, s.x * r);
                }
            }
        }
        __syncthreads();
        if (tid < 12) {
            float v = istate[tid];
#pragma unroll 4
            for (int tt = 0; tt < TBS; ++tt) {
                float2 ab = iAB[tt * 12 + tid];
                float A = ab.x, B = ab.y;
                float A2 = A * A, A4 = A2 * A2;
                float A6 = A4 * A2;
                float B6 = B * (1.f + A) * (1.f + A2 + A4);
                viter[tt * 13 + tid] = v;
                v = fmaf(A6, v, B6);
            }
            istate[tid] = v;
        }
        __syncthreads();
        for (int c = 0; c < nchunks; ++c) {
            int ps = TL.ch_ps[c], pe = TL.ch_pe[c];
            int gs0 = TL.ch_gs[c], ge0 = TL.ch_ge[c];
            int npc = pe - ps;
            for (int w = tid; w < npc * TBS; w += 512) {
                int m = w >> 7, tt = w & (TBS - 1);
                int posi = ps + m;
                int unit = TL.ord[posi];
                float pn[6], pd[6];
#pragma unroll
                for (int u = 0; u < 6; ++u) { pn[u] = TL.cn0[unit]; pd[u] = TL.cd0[unit]; }
                int ncp = TL.ncp[unit];
                for (int e = 0; e < ncp; ++e) {
                    int sl = TL.cp_pre[unit][e];
                    float a = TL.cp_a[unit][e], bb = TL.cp_b[unit][e];
                    float w_ = TL.cp_w[unit][e], ev = TL.cp_e[unit][e];
#pragma unroll
                    for (int u = 0; u < 6; ++u) {
                        float gq = sgm(a, bb, vtraj[(sl * TBS + tt) * 7 + u]);
                        pn[u] = fmaf(ev, gq, pn[u]);
                        pd[u] = fmaf(w_, gq, pd[u]);
                    }
                }
                int nip = TL.nip[unit];
                for (int e = 0; e < nip; ++e) {
                    int ii = TL.ip_i[unit][e];
                    float2 ab = iAB[tt * 12 + ii];
                    float vi = viter[tt * 13 + ii];
                    float a = TL.ip_a[unit][e], bb = TL.ip_b[unit][e];
                    float w_ = TL.ip_w[unit][e], ev = TL.ip_e[unit][e];
#pragma unroll
                    for (int u = 0; u < 6; ++u) {
                        float gq = sgm(a, bb, vi);
                        pn[u] = fmaf(ev, gq, pn[u]);
                        pd[u] = fmaf(w_, gq, pd[u]);
                        vi = fmaf(ab.x, vi, ab.y);
                    }
                }
                if (TL.aff[posi]) {
                    float cmt = TL.cmt[unit];
                    float Ac = 1.f, Bc = 0.f;
#pragma unroll
                    for (int u = 0; u < 6; ++u) {
                        float r = frcp(pd[u]);
                        float Au = cmt * r, Bu = pn[u] * r;
                        pnpd[(m * TBS + tt) * 7 + u] = make_float2(Au, Bu);
                        Bc = fmaf(Au, Bc, Bu);
                        Ac *= Au;
                    }
                    comp[m * TBS + tt] = make_float2(Ac, Bc);
                } else {
#pragma unroll
                    for (int u = 0; u < 6; ++u)
                        pnpd[(m * TBS + tt) * 7 + u] = make_float2(pn[u], pd[u]);
                }
            }
            __syncthreads();
            if (tid < ge0 - gs0) {
                int g = gs0 + tid;
                int gs = TL.grp_start[g], ge = TL.grp_start[g + 1], gsz = ge - gs;
                int m0 = gs - ps;
                if (gsz == 1) {
                    int unit = TL.ord[gs];
                    float v = gstate[gs];
                    if (TL.aff[gs]) {
#pragma unroll 4
                        for (int tt = 0; tt < TBS; ++tt) {
                            vstart[m0 * TBS + tt] = v;
                            float2 cc = comp[m0 * TBS + tt];
                            v = fmaf(cc.x, v, cc.y);
                        }
                    } else {
                        float ga = TL.gp_a[unit][0], gb = TL.gp_b[unit][0];
                        float gw = TL.gp_w[unit][0], gev = TL.gp_e[unit][0];
                        float cmt = TL.cmt[unit];
                        int ntj = TL.need_traj[gs];
                        int sl = TL.traj_slot[gs];
                        for (int tt = 0; tt < TBS; ++tt) {
#pragma unroll
                            for (int u = 0; u < 6; ++u) {
                                if (ntj) vtraj[(sl * TBS + tt) * 7 + u] = v;
                                float2 pp2 = pnpd[(m0 * TBS + tt) * 7 + u];
                                float E = ex2(fmaf(ga, v, gb));
                                float P = fmaf(cmt, v, pp2.x);
                                float N = fmaf(P, E, P + gev);
                                float Dd = fmaf(pp2.y, E, pp2.y + gw);
                                v = N * frcp(Dd);
                            }
                        }
                    }
                    gstate[gs] = v;
                } else {
                    float sv[CHK], nv[CHK];
#pragma unroll
                    for (int mm = 0; mm < CHK; ++mm) if (mm < gsz) sv[mm] = gstate[gs + mm];
                    for (int tt = 0; tt < TBS; ++tt) {
#pragma unroll
                        for (int u = 0; u < 6; ++u) {
#pragma unroll
                            for (int mm = 0; mm < CHK; ++mm)
                                if (mm < gsz && TL.need_traj[gs + mm])
                                    vtraj[(TL.traj_slot[gs + mm] * TBS + tt) * 7 + u] = sv[mm];
#pragma unroll
                            for (int mm = 0; mm < CHK; ++mm) {
                                if (mm < gsz) {
                                    int unit = TL.ord[gs + mm];
                                    float2 pp2 = pnpd[((m0 + mm) * TBS + tt) * 7 + u];
                                    float wn = pp2.x, wd = pp2.y;
                                    int ngpu = TL.ngp[unit];
#pragma unroll
                                    for (int e = 0; e < 6; ++e) {
                                        if (e < ngpu) {
                                            float vp = sv[TL.gp_pre[unit][e]];
                                            float gq = sgm(TL.gp_a[unit][e], TL.gp_b[unit][e], vp);
                                            wn = fmaf(TL.gp_e[unit][e], gq, wn);
                                            wd = fmaf(TL.gp_w[unit][e], gq, wd);
                                        }
                                    }
                                    nv[mm] = fmaf(TL.cmt[unit], sv[mm], wn) * frcp(wd);
                                }
                            }
#pragma unroll
                            for (int mm = 0; mm < CHK; ++mm) if (mm < gsz) sv[mm] = nv[mm];
                        }
                    }
#pragma unroll
                    for (int mm = 0; mm < CHK; ++mm) if (mm < gsz) gstate[gs + mm] = sv[mm];
                }
            }
            __syncthreads();
            for (int w = tid; w < npc * TBS; w += 512) {
                int m = w >> 7, tt = w & (TBS - 1);
                int posi = ps + m;
                if (TL.aff[posi] && TL.need_traj[posi]) {
                    int sl = TL.traj_slot[posi];
                    float v = vstart[m * TBS + tt];
#pragma unroll
                    for (int u = 0; u < 6; ++u) {
                        vtraj[(sl * TBS + tt) * 7 + u] = v;
                        float2 ab = pnpd[(m * TBS + tt) * 7 + u];
                        v = fmaf(ab.x, v, ab.y);
                    }
                }
            }
            __syncthreads();
        }
    }
    if (tid < 20 && tid < TL.npos) vstate[b * 32 + TL.ord[tid]] = gstate[tid];
    if (tid < 12) vstate[b * 32 + 20 + tid] = istate[tid];
    if (lastChunk) {
        __syncthreads();
        if (tid == 0) out[b] = fmaf(gstate[TL.pos[0]], ow[0], ob[0]);
    }
}

extern "C" void kernel_launch(void* const* d_in, const int* in_sizes, int n_in,
                              void* d_out, int out_size, void* d_ws, size_t ws_size,
                              hipStream_t stream) {
    fp x     = (fp)d_in[0];
    fp d1w   = (fp)d_in[1];
    fp d1b   = (fp)d_in[2];
    fp d2w   = (fp)d_in[3];
    fp d2b   = (fp)d_in[4];
    fp iw    = (fp)d_in[5];
    fp ib    = (fp)d_in[6];
    fp ow    = (fp)d_in[7];
    fp ob    = (fp)d_in[8];
    fp gleak = (fp)d_in[9];
    fp vleak = (fp)d_in[10];
    fp cm    = (fp)d_in[11];
    fp wsyn  = (fp)d_in[12];
    fp mu    = (fp)d_in[13];
    fp sigma = (fp)d_in[14];
    fp erev  = (fp)d_in[15];
    fp sw    = (fp)d_in[16];
    fp smu   = (fp)d_in[17];
    fp ssg   = (fp)d_in[18];
    fp serev = (fp)d_in[19];
    const int* spm   = (const int*)d_in[20];
    const int* smask = (const int*)d_in[21];

    char* wsb = (char*)d_ws;
    Tables*   T = (Tables*)wsb;
    DenseTab* D = (DenseTab*)(wsb + WS_DTAB);
    float*   bnd = (float*)(wsb + WS_BND);
    float2*   Mg = (float2*)(wsb + WS_MG);
    float* vstate = (float*)(wsb + WS_VST);
    float2* sensI = (float2*)(wsb + WS_SENSI);

    size_t per_t = (size_t)NB * 12 * sizeof(float2);     // 24576 B
    int CT = TBS;
    if (ws_size > WS_SENSI) {
        size_t m = (ws_size - WS_SENSI) / per_t;
        int ct = TBS;
        while (ct < NT && (size_t)(ct * 2) <= m) ct *= 2;
        CT = ct;
    }

    build_tables<<<1, 64, 0, stream>>>(wsyn, mu, sigma, erev, spm,
                                       sw, smu, ssg, serev, smask,
                                       cm, gleak, vleak, d1b, T, D);
    sector_all<<<1, 256, 0, stream>>>(d1w, d2w, iw, bnd, Mg);

    int nch = NT / CT;
    for (int c = 0; c < nch; ++c) {
        int t0 = c * CT;
        dense_general<<<512, 256, 0, stream>>>(x, d1w, d1b, d2w, d2b, iw, ib, D, sensI, t0, CT);
        solve<<<NB, 512, 0, stream>>>(x, sensI, T, D, Mg, bnd, d2b, iw, ib,
                                      ow, ob, vstate, t0, CT, (float*)d_out);
    }
}

// Round 20
// 249.020 us; speedup vs baseline: 2.1336x; 2.1336x over previous
//
#include <hip/hip_runtime.h>
#include <math.h>

#define NB 256
#define NT 1024
#define NUNF 6
#define TBS 128
#define CHK 8
#define NTJMAX 12
#define L2E 1.44269504088896340736f
#define PI_F 3.14159265358979324f

typedef const float* fp;

extern "C" __device__ float __ocml_exp2_f32(float);
__device__ __forceinline__ float frcp(float x) { return __builtin_amdgcn_rcpf(x); }
__device__ __forceinline__ float ex2(float x) { return __ocml_exp2_f32(x); }
__device__ __forceinline__ float sgm(float a, float b, float v) { return frcp(1.f + ex2(fmaf(a, v, b))); }

struct Tables {
    int ngroups, npos, nchunks, ntraj;
    int grp_start[21];
    int ord[20];
    int pos[20];
    int aff[20];
    int need_traj[20];
    int traj_slot[20];
    int ch_ps[20], ch_pe[20], ch_gs[20], ch_ge[20];
    int ncp[20], nip[20], ngp[20];
    float cmt[20], cn0[20], cd0[20];
    float icmt[12];
    int   cp_pre[20][8];          // traj SLOT of the pre unit
    float cp_a[20][8], cp_b[20][8], cp_w[20][8], cp_e[20][8];
    int   ip_i[20][12];
    float ip_a[20][12], ip_b[20][12], ip_w[20][12], ip_e[20][12];
    int   gp_pre[20][6];
    float gp_a[20][6], gp_b[20][6], gp_w[20][6], gp_e[20][6];
};

struct DenseTab {
    int cnt[12];
    float in0[12], id0[12];
    int   pre[12][32];
    float a[12][32], b[12][32], w[12][32], e[12][32];
    int homog, maxcnt;
};

// ws layout
#define WS_DTAB   16384
#define WS_BND    24576
#define WS_BMASK  25600
#define WS_MG     32768
#define WS_VST    98304
#define WS_SENSI  131072

// ---------------- K0: wiring analysis, lane-parallel in LDS ----------------
__global__ void build_tables(fp wsyn, fp mu, fp sigma, fp erev, const int* spm,
                             fp sw, fp smu, fp ssg, fp serev, const int* smask,
                             fp cm, fp gleak, fp vleak, fp d1b, Tables* T, DenseTab* D) {
    __shared__ int   spmL[1024], smkL[1024];
    __shared__ float wL[1024], muL[1024], sgL[1024], evL[1024];
    __shared__ float swL[1024], smuL[1024], ssgL[1024], sevL[1024];
    __shared__ float cmL[32], glL[32], vlL[32];
    __shared__ int premaskL[20], ancL[20], rootL[20], depUL[20], keyL[20], posL[20], ordL[20];
    __shared__ int ngpL[20], ntjL[20], slotU[20];
    __shared__ int neededS;
    __shared__ float habs[64];
    __shared__ int cntS[12];
    int tid = threadIdx.x;
    for (int k = tid; k < 1024; k += 64) {
        spmL[k] = spm[k]; wL[k] = wsyn[k]; muL[k] = mu[k]; sgL[k] = sigma[k]; evL[k] = erev[k];
        smkL[k] = smask[k]; swL[k] = sw[k]; smuL[k] = smu[k]; ssgL[k] = ssg[k]; sevL[k] = serev[k];
    }
    if (tid < 32) { cmL[tid] = cm[tid]; glL[tid] = gleak[tid]; vlL[tid] = vleak[tid]; }
    habs[tid] = fmaxf(fabsf(d1b[tid]), fabsf(d1b[tid + 64]));
    __syncthreads();
    if (tid < 20) {
        int pm = 0;
        for (int i = 0; i < 20; ++i) if (spmL[i * 32 + tid]) pm |= 1 << i;
        premaskL[tid] = pm;
        ancL[tid] = pm;
    }
    __syncthreads();
    for (int it = 0; it < 20; ++it) {
        int a = 0;
        if (tid < 20) {
            a = ancL[tid];
            int pm = premaskL[tid];
            for (int i = 0; i < 20; ++i) if ((pm >> i) & 1) a |= ancL[i];
        }
        __syncthreads();
        if (tid < 20) ancL[tid] = a;
        __syncthreads();
    }
    if (tid == 0) neededS = ancL[0] | 1;
    __syncthreads();
    int needed = neededS;
    if (tid < 20) {
        int r = tid;
        if ((needed >> tid) & 1) {
            int aj = ancL[tid];
            for (int i = 0; i < 20; ++i)
                if (i < r && ((needed >> i) & 1) && ((aj >> i) & 1) && ((ancL[i] >> tid) & 1)) r = i;
        }
        rootL[tid] = r;
        depUL[tid] = 0;
    }
    __syncthreads();
    for (int it = 0; it < 21; ++it) {
        int d = 0;
        if (tid < 20 && ((needed >> tid) & 1)) {
            int pm = premaskL[tid], myr = rootL[tid];
            for (int i = 0; i < 20; ++i)
                if (((pm >> i) & 1) && rootL[i] != myr) d = max(d, depUL[i] + 1);
        }
        __syncthreads();
        if (tid < 20 && d > depUL[tid]) depUL[tid] = d;
        __syncthreads();
    }
    if (tid < 20) {
        int key = 0x7FFFFFFF;
        if ((needed >> tid) & 1) {
            int myr = rootL[tid], dg = 0;
            for (int i = 0; i < 20; ++i)
                if (((needed >> i) & 1) && rootL[i] == myr) dg = max(dg, depUL[i]);
            key = dg * 32 + myr;
        }
        keyL[tid] = key;
    }
    __syncthreads();
    if (tid < 20) {
        int mykey = keyL[tid];
        int p = 0;
        for (int k = 0; k < 20; ++k)
            if (keyL[k] < mykey || (keyL[k] == mykey && k < tid)) ++p;
        posL[tid] = p;
        if (p < 20) ordL[p] = tid;
    }
    __syncthreads();
    if (tid < 20) {
        int nt = 0;
        if ((needed >> tid) & 1)
            for (int j = 0; j < 20; ++j)
                if (j != tid && ((needed >> j) & 1) && spmL[tid * 32 + j]) { nt = 1; break; }
        ntjL[tid] = nt;
    }
    __syncthreads();
    if (tid == 0) {
        int s = 0;
        for (int p = 0; p < 20; ++p) { int u = ordL[p]; slotU[u] = s; s += ntjL[u]; }
        T->ntraj = s;
    }
    __syncthreads();
    if (tid < 20) {
        int j = tid, cc = 0, ci = 0, cg = 0;
        T->cmt[j] = cmL[j] * (float)NUNF;
        T->cn0[j] = glL[j] * vlL[j];
        T->cd0[j] = cmL[j] * (float)NUNF + glL[j] + 1e-8f;
        if ((needed >> j) & 1) {
            int myr = rootL[j];
            int mystart = posL[myr];
            for (int i = 0; i < 32; ++i) {
                int p = i * 32 + j;
                if (!spmL[p]) continue;
                float sg = sgL[p];
                float a = -sg * L2E, b = sg * muL[p] * L2E;
                float w = wL[p], e = w * evL[p];
                if (i >= 20) {
                    T->ip_i[j][ci] = i - 20;
                    T->ip_a[j][ci] = a; T->ip_b[j][ci] = b; T->ip_w[j][ci] = w; T->ip_e[j][ci] = e;
                    ++ci;
                } else if (rootL[i] == myr) {
                    T->gp_pre[j][cg] = posL[i] - mystart;
                    T->gp_a[j][cg] = a; T->gp_b[j][cg] = b; T->gp_w[j][cg] = w; T->gp_e[j][cg] = e;
                    ++cg;
                } else {
                    T->cp_pre[j][cc] = slotU[i];
                    T->cp_a[j][cc] = a; T->cp_b[j][cc] = b; T->cp_w[j][cc] = w; T->cp_e[j][cc] = e;
                    ++cc;
                }
            }
        }
        T->ncp[j] = cc; T->nip[j] = ci; T->ngp[j] = cg;
        ngpL[j] = cg;
    }
    if (tid < 12) {
        T->icmt[tid] = cmL[20 + tid] * (float)NUNF;
        int unit = 20 + tid, cnt = 0;
        for (int s = 0; s < 32; ++s) {
            int p = s * 32 + unit;
            if (!smkL[p]) continue;
            float sg = ssgL[p];
            D->pre[tid][cnt] = s;
            D->a[tid][cnt] = -sg * L2E;
            D->b[tid][cnt] = sg * smuL[p] * L2E;
            D->w[tid][cnt] = swL[p];
            D->e[tid][cnt] = swL[p] * sevL[p];
            ++cnt;
        }
        for (int c = cnt; c < 32; ++c) {
            D->pre[tid][c] = 0; D->a[tid][c] = 0.f; D->b[tid][c] = 0.f;
            D->w[tid][c] = 0.f; D->e[tid][c] = 0.f;
        }
        D->cnt[tid] = cnt;
        cntS[tid] = cnt;
        D->in0[tid] = glL[unit] * vlL[unit];
        D->id0[tid] = cmL[unit] * (float)NUNF + glL[unit] + 1e-8f;
    }
    __syncthreads();
    if (tid == 0) {
        int npos = __popc(needed & 0xFFFFF);
        T->npos = npos;
        int ng = 0, prevkey = -1;
        for (int p = 0; p < npos; ++p) {
            int u = ordL[p];
            if (keyL[u] != prevkey) { T->grp_start[ng] = p; ++ng; prevkey = keyL[u]; }
        }
        T->ngroups = ng;
        for (int g = ng; g <= 20; ++g) T->grp_start[g] = npos;
        for (int p = 0; p < 20; ++p) T->ord[p] = (p < npos) ? ordL[p] : 0;
        for (int j = 0; j < 20; ++j) T->pos[j] = posL[j];
        for (int g = 0; g < ng; ++g) {
            int gs = T->grp_start[g], ge = T->grp_start[g + 1], gsz = ge - gs;
            for (int p = gs; p < ge; ++p)
                T->aff[p] = (gsz == 1 && ngpL[ordL[p]] == 0) ? 1 : 0;
        }
        for (int p = npos; p < 20; ++p) T->aff[p] = 0;
        for (int p = 0; p < 20; ++p) {
            int u = ordL[p];
            T->need_traj[p] = ntjL[u];
            T->traj_slot[p] = slotU[u];
        }
        int nchunks = 0, g = 0;
        while (g < ng) {
            int lvl = keyL[ordL[T->grp_start[g]]] / 32;
            int ge = g;
            while (ge < ng && keyL[ordL[T->grp_start[ge]]] / 32 == lvl) ++ge;
            int cs = g;
            while (cs < ge) {
                int ce = cs, acc = 0;
                while (ce < ge) {
                    int gsz = T->grp_start[ce + 1] - T->grp_start[ce];
                    if (acc + gsz > CHK && ce > cs) break;
                    acc += gsz; ++ce;
                    if (acc >= CHK) break;
                }
                T->ch_gs[nchunks] = cs; T->ch_ge[nchunks] = ce;
                T->ch_ps[nchunks] = T->grp_start[cs]; T->ch_pe[nchunks] = T->grp_start[ce];
                ++nchunks;
                cs = ce;
            }
            g = ge;
        }
        T->nchunks = nchunks;
        float hm = 0.f;
        for (int k = 0; k < 64; ++k) hm = fmaxf(hm, habs[k]);
        D->homog = (hm == 0.f) ? 1 : 0;
        int mc = 0;
        for (int k = 0; k < 12; ++k) mc = max(mc, cntS[k]);
        D->maxcnt = mc;
    }
}

// ---------------- K0b: boundary angles of the 128 origin-lines, sorted (1 block) ----------------
__global__ void sector_prep(fp d1w, float* bnd, int* bmask) {
    __shared__ float ang[256];
    __shared__ float uS[128], vS[128];
    int tid = threadIdx.x;
    if (tid < 128) { uS[tid] = d1w[tid]; vS[tid] = d1w[128 + tid]; }
    __syncthreads();
    {
        int k = tid & 127;
        float al = atan2f(vS[k], uS[k]);
        float bb = (tid < 128) ? al + 1.57079632679489662f : al - 1.57079632679489662f;
        if (bb > PI_F) bb -= 2.f * PI_F;
        if (bb <= -PI_F) bb += 2.f * PI_F;
        ang[tid] = bb;
    }
    __syncthreads();
    for (int k = 2; k <= 256; k <<= 1) {
        for (int j = k >> 1; j > 0; j >>= 1) {
            int ixj = tid ^ j;
            if (ixj > tid) {
                float a0 = ang[tid], a1 = ang[ixj];
                bool up = ((tid & k) == 0);
                if ((a0 > a1) == up) { ang[tid] = a1; ang[ixj] = a0; }
            }
            __syncthreads();
        }
    }
    bnd[tid] = ang[tid];
    float lo = ang[tid];
    float hi = (tid < 255) ? ang[tid + 1] : ang[0] + 2.f * PI_F;
    float tm = 0.5f * (lo + hi);
    float ct = cosf(tm), st = sinf(tm);
    for (int w = 0; w < 4; ++w) {
        int m = 0;
        for (int kk = 0; kk < 32; ++kk) {
            int k = w * 32 + kk;
            if (fmaf(uS[k], ct, vS[k] * st) > 0.f) m |= 1 << kk;
        }
        bmask[tid * 4 + w] = m;
    }
}

// ---------------- K0c: per-sector collapsed 2x32 dense map (256 blocks!) ----------------
__global__ void sector_M(fp d1w, fp d2w, fp iw, const int* bmask, float2* Mg) {
    int s = blockIdx.x, j = threadIdx.x;
    if (j >= 32) return;
    float acc0 = 0.f, acc1 = 0.f;
#pragma unroll
    for (int w = 0; w < 4; ++w) {
        int mm = bmask[s * 4 + w];
        for (int kk = 0; kk < 32; ++kk) {
            if ((mm >> kk) & 1) {
                int k = w * 32 + kk;
                float w2 = d2w[k * 32 + j];
                acc0 = fmaf(d1w[k], w2, acc0);
                acc1 = fmaf(d1w[128 + k], w2, acc1);
            }
        }
    }
    float iwj = iw[j];
    Mg[s * 32 + j] = make_float2(acc0 * iwj, acc1 * iwj);
}

// ---------------- K1b: general fallback dense; early-exits when homog ----------------
__global__ __launch_bounds__(256) void dense_general(
    fp x, fp d1w, fp d1b, fp d2w, fp d2b, fp iw, fp ib,
    const DenseTab* __restrict__ Dg, float2* sensI, int t0, int CT) {
    if (Dg->homog != 0) return;
    __shared__ float W2s[4096];
    __shared__ float W1s[256], b1s[128];
    __shared__ float b2q[32], iwq[32], ibq[32];
    __shared__ float4 tabT[416];
    __shared__ int   preT[416];
    __shared__ int   cntL[12];
    __shared__ float in0L[12], id0L[12];
    __shared__ float hbuf[4][128][20];
    __shared__ float ibuf[4][16][33];
    int tid = threadIdx.x;
    for (int idx = tid; idx < 384; idx += 256) {
        int d = idx >> 5, e = idx & 31;
        int sl = e * 13 + d;
        tabT[sl] = make_float4(Dg->a[d][e], Dg->b[d][e], Dg->w[d][e], Dg->e[d][e]);
        preT[sl] = Dg->pre[d][e];
    }
    if (tid < 12) { cntL[tid] = Dg->cnt[tid]; in0L[tid] = Dg->in0[tid]; id0L[tid] = Dg->id0[tid]; }
    for (int p = tid; p < 4096; p += 256) W2s[p] = d2w[p];
    if (tid < 256) W1s[tid] = d1w[tid];
    if (tid < 128) b1s[tid] = d1b[tid];
    if (tid < 32) { b2q[tid] = d2b[tid]; iwq[tid] = iw[tid]; ibq[tid] = ib[tid]; }
    __syncthreads();
    int wid = tid >> 6, lane = tid & 63;
    float* hb = (float*)hbuf[wid];
    float* ibf = (float*)ibuf[wid];
    const float2* x2 = (const float2*)x;
    int gw = blockIdx.x * 4 + wid;
    int nw = gridDim.x * 4;
    int pass_total = (NB * CT) >> 4;
    int itd1 = lane >> 2, kq = lane & 3;
    int j = lane & 31, half = lane >> 5;
    for (int pass = gw; pass < pass_total; pass += nw) {
        int cg0 = pass * 16;
        {
            int cg = cg0 + itd1;
            int lt = cg >> 8, b = cg & 255;
            float2 xv = x2[b * NT + (t0 + lt)];
#pragma unroll 8
            for (int i = 0; i < 32; ++i) {
                int k = kq + 4 * i;
                float hk = fmaf(xv.y, W1s[128 + k], fmaf(xv.x, W1s[k], b1s[k]));
                hb[k * 20 + itd1] = hk > 0.f ? hk : 0.f;
            }
        }
        __builtin_amdgcn_wave_barrier();
        {
            float a0=0,a1=0,a2=0,a3=0,a4=0,a5=0,a6=0,a7=0;
#pragma unroll 4
            for (int k = 0; k < 128; ++k) {
                float w2 = W2s[k * 32 + j];
                float4 ha = *(const float4*)&hb[k * 20 + half * 8];
                float4 hbv = *(const float4*)&hb[k * 20 + half * 8 + 4];
                a0 = fmaf(ha.x, w2, a0); a1 = fmaf(ha.y, w2, a1);
                a2 = fmaf(ha.z, w2, a2); a3 = fmaf(ha.w, w2, a3);
                a4 = fmaf(hbv.x, w2, a4); a5 = fmaf(hbv.y, w2, a5);
                a6 = fmaf(hbv.z, w2, a6); a7 = fmaf(hbv.w, w2, a7);
            }
            float bb = b2q[j], iww = iwq[j], ibb = ibq[j];
            ibf[(half*8+0)*33+j] = fmaf(a0+bb, iww, ibb);
            ibf[(half*8+1)*33+j] = fmaf(a1+bb, iww, ibb);
            ibf[(half*8+2)*33+j] = fmaf(a2+bb, iww, ibb);
            ibf[(half*8+3)*33+j] = fmaf(a3+bb, iww, ibb);
            ibf[(half*8+4)*33+j] = fmaf(a4+bb, iww, ibb);
            ibf[(half*8+5)*33+j] = fmaf(a5+bb, iww, ibb);
            ibf[(half*8+6)*33+j] = fmaf(a6+bb, iww, ibb);
            ibf[(half*8+7)*33+j] = fmaf(a7+bb, iww, ibb);
        }
        __builtin_amdgcn_wave_barrier();
#pragma unroll
        for (int r = 0; r < 3; ++r) {
            int task = r * 64 + lane;
            int it = task / 12;
            int d = task - it * 12;
            int cnt = cntL[d];
            float wn = in0L[d], wd = id0L[d];
            for (int e = 0; e < cnt; ++e) {
                int sl = e * 13 + d;
                float4 tb = tabT[sl];
                float gq = frcp(1.f + ex2(fmaf(tb.x, ibf[it * 33 + preT[sl]], tb.y)));
                wn = fmaf(tb.w, gq, wn);
                wd = fmaf(tb.z, gq, wd);
            }
            int cg = cg0 + it;
            int lt = cg >> 8, b = cg & 255;
            sensI[(size_t)(b * CT + lt) * 12 + d] = make_float2(wn, wd);
        }
        __builtin_amdgcn_wave_barrier();
    }
}

// ---------------- K2: fused solver: coalesced inline dense (homog) + level-parallel LTC ----------------
__global__ __launch_bounds__(512) void solve(
    fp x, const float2* __restrict__ sensI,
    const Tables* __restrict__ Tg, const DenseTab* __restrict__ Dg,
    const float2* __restrict__ Mg, const float* __restrict__ bndg,
    fp d2b, fp iw, fp ib,
    fp ow, fp ob, float* vstate, int t0, int CT, float* out) {
    __shared__ Tables TL;
    __shared__ float2 iAB[TBS * 12];
    __shared__ float viter[TBS * 13];
    __shared__ float vtraj[NTJMAX * TBS * 7];
    __shared__ float2 pnpd[CHK * TBS * 7];       // aliased as inp scratch during dense phase
    __shared__ float2 comp[CHK * TBS];
    __shared__ float vstart[CHK * TBS];
    __shared__ float gstate[20], istate[12];
    __shared__ float bndL[256];
    __shared__ float4 tabT[416];
    __shared__ int   preT[416];
    __shared__ float cjL[32];
    __shared__ float in0L[12], id0L[12];
    __shared__ int   secS[128];
    __shared__ float x0S[128], x1S[128];
    int tid = threadIdx.x;
    int b = blockIdx.x;
    {
        const int nw = (int)(sizeof(Tables) / 4);
        const int* src = (const int*)Tg;
        int* dst = (int*)&TL;
        for (int k = tid; k < nw; k += 512) dst[k] = src[k];
    }
    int homog = Dg->homog;
    int cntmax = Dg->maxcnt;
    if (homog) {
        for (int idx = tid; idx < 384; idx += 512) {
            int d = idx >> 5, e = idx & 31;
            int sl = e * 13 + d;
            tabT[sl] = make_float4(Dg->a[d][e], Dg->b[d][e], Dg->w[d][e], Dg->e[d][e]);
            preT[sl] = Dg->pre[d][e];
        }
        if (tid < 256) bndL[tid] = bndg[tid];
        if (tid < 32) cjL[tid] = fmaf(d2b[tid], iw[tid], ib[tid]);
        if (tid < 12) { in0L[tid] = Dg->in0[tid]; id0L[tid] = Dg->id0[tid]; }
    }
    __syncthreads();
    if (tid < 20 && tid < TL.npos)
        gstate[tid] = (t0 == 0) ? 0.f : vstate[b * 32 + TL.ord[tid]];
    if (tid < 12)
        istate[tid] = (t0 == 0) ? 0.f : vstate[b * 32 + 20 + tid];
    __syncthreads();
    int ntiles = CT / TBS;
    bool lastChunk = (t0 + CT == NT);
    const float2* x2 = (const float2*)x;
    int nchunks = TL.nchunks;
    for (int tile = 0; tile < ntiles; ++tile) {
        int tbase = tile * TBS;
        if (homog) {
            // ---- phase 1: sector + x per item (128 lanes) ----
            if (tid < 128) {
                float2 xv = x2[(size_t)b * NT + (t0 + tbase + tid)];
                x0S[tid] = xv.x; x1S[tid] = xv.y;
                float th = atan2f(xv.y, xv.x);
                int sec;
                if (th < bndL[0]) sec = 255;
                else {
                    int lo = 0, hi = 255;
#pragma unroll
                    for (int it7 = 0; it7 < 8; ++it7) {
                        int mid = (lo + hi + 1) >> 1;
                        if (bndL[mid] <= th) lo = mid; else hi = mid - 1;
                    }
                    sec = lo;
                }
                secS[tid] = sec;
            }
            __syncthreads();
            // ---- phase 2: inp via COALESCED Mg reads (j lane-consecutive) ----
            float* ibufL = (float*)pnpd;
            {
                int j = tid & 31, grp = tid >> 5;   // 16 groups x 8 items
                float cj = cjL[j];
#pragma unroll
                for (int c = 0; c < 8; ++c) {
                    int item = grp * 8 + c;
                    float2 m = Mg[secS[item] * 32 + j];
                    ibufL[item * 33 + j] = fmaf(x0S[item], m.x, fmaf(x1S[item], m.y, cj));
                }
            }
            __syncthreads();
            // ---- phase 3: gate sums -> iAB (1536 tasks, 3 rounds) ----
#pragma unroll
            for (int rb = 0; rb < 3; ++rb) {
                int task = rb * 512 + tid;
                int item = task / 12;
                int dd = task - item * 12;
                float wn = in0L[dd], wd = id0L[dd];
                for (int e = 0; e < cntmax; ++e) {
                    int sl = e * 13 + dd;
                    float4 tb = tabT[sl];
                    float gq = frcp(1.f + ex2(fmaf(tb.x, ibufL[item * 33 + preT[sl]], tb.y)));
                    wn = fmaf(tb.w, gq, wn);
                    wd = fmaf(tb.z, gq, wd);
                }
                float r = frcp(wd);
                iAB[item * 12 + dd] = make_float2(TL.icmt[dd] * r, wn * r);
            }
        } else {
            for (int w = tid; w < TBS * 16; w += 512) {
                int tt = w >> 4, ii = w & 15;
                if (ii < 12) {
                    float2 s = sensI[(size_t)(b * CT + tbase + tt) * 12 + ii];
                    float r = frcp(s.y);
                    iAB[tt * 12 + ii] = make_float2(TL.icmt[ii] * r, s.x * r);
                }
            }
        }
        __syncthreads();
        if (tid < 12) {
            float v = istate[tid];
#pragma unroll 4
            for (int tt = 0; tt < TBS; ++tt) {
                float2 ab = iAB[tt * 12 + tid];
                float A = ab.x, B = ab.y;
                float A2 = A * A, A4 = A2 * A2;
                float A6 = A4 * A2;
                float B6 = B * (1.f + A) * (1.f + A2 + A4);
                viter[tt * 13 + tid] = v;
                v = fmaf(A6, v, B6);
            }
            istate[tid] = v;
        }
        __syncthreads();
        for (int c = 0; c < nchunks; ++c) {
            int ps = TL.ch_ps[c], pe = TL.ch_pe[c];
            int gs0 = TL.ch_gs[c], ge0 = TL.ch_ge[c];
            int npc = pe - ps;
            for (int w = tid; w < npc * TBS; w += 512) {
                int m = w >> 7, tt = w & (TBS - 1);
                int posi = ps + m;
                int unit = TL.ord[posi];
                float pn[6], pd[6];
#pragma unroll
                for (int u = 0; u < 6; ++u) { pn[u] = TL.cn0[unit]; pd[u] = TL.cd0[unit]; }
                int ncp = TL.ncp[unit];
                for (int e = 0; e < ncp; ++e) {
                    int sl = TL.cp_pre[unit][e];
                    float a = TL.cp_a[unit][e], bb = TL.cp_b[unit][e];
                    float w_ = TL.cp_w[unit][e], ev = TL.cp_e[unit][e];
#pragma unroll
                    for (int u = 0; u < 6; ++u) {
                        float gq = sgm(a, bb, vtraj[(sl * TBS + tt) * 7 + u]);
                        pn[u] = fmaf(ev, gq, pn[u]);
                        pd[u] = fmaf(w_, gq, pd[u]);
                    }
                }
                int nip = TL.nip[unit];
                for (int e = 0; e < nip; ++e) {
                    int ii = TL.ip_i[unit][e];
                    float2 ab = iAB[tt * 12 + ii];
                    float vi = viter[tt * 13 + ii];
                    float a = TL.ip_a[unit][e], bb = TL.ip_b[unit][e];
                    float w_ = TL.ip_w[unit][e], ev = TL.ip_e[unit][e];
#pragma unroll
                    for (int u = 0; u < 6; ++u) {
                        float gq = sgm(a, bb, vi);
                        pn[u] = fmaf(ev, gq, pn[u]);
                        pd[u] = fmaf(w_, gq, pd[u]);
                        vi = fmaf(ab.x, vi, ab.y);
                    }
                }
                if (TL.aff[posi]) {
                    float cmt = TL.cmt[unit];
                    float Ac = 1.f, Bc = 0.f;
#pragma unroll
                    for (int u = 0; u < 6; ++u) {
                        float r = frcp(pd[u]);
                        float Au = cmt * r, Bu = pn[u] * r;
                        pnpd[(m * TBS + tt) * 7 + u] = make_float2(Au, Bu);
                        Bc = fmaf(Au, Bc, Bu);
                        Ac *= Au;
                    }
                    comp[m * TBS + tt] = make_float2(Ac, Bc);
                } else {
#pragma unroll
                    for (int u = 0; u < 6; ++u)
                        pnpd[(m * TBS + tt) * 7 + u] = make_float2(pn[u], pd[u]);
                }
            }
            __syncthreads();
            if (tid < ge0 - gs0) {
                int g = gs0 + tid;
                int gs = TL.grp_start[g], ge = TL.grp_start[g + 1], gsz = ge - gs;
                int m0 = gs - ps;
                if (gsz == 1) {
                    int unit = TL.ord[gs];
                    float v = gstate[gs];
                    if (TL.aff[gs]) {
#pragma unroll 4
                        for (int tt = 0; tt < TBS; ++tt) {
                            vstart[m0 * TBS + tt] = v;
                            float2 cc = comp[m0 * TBS + tt];
                            v = fmaf(cc.x, v, cc.y);
                        }
                    } else {
                        float ga = TL.gp_a[unit][0], gb = TL.gp_b[unit][0];
                        float gw = TL.gp_w[unit][0], gev = TL.gp_e[unit][0];
                        float cmt = TL.cmt[unit];
                        int ntj = TL.need_traj[gs];
                        int sl = TL.traj_slot[gs];
                        for (int tt = 0; tt < TBS; ++tt) {
#pragma unroll
                            for (int u = 0; u < 6; ++u) {
                                if (ntj) vtraj[(sl * TBS + tt) * 7 + u] = v;
                                float2 pp2 = pnpd[(m0 * TBS + tt) * 7 + u];
                                float E = ex2(fmaf(ga, v, gb));
                                float P = fmaf(cmt, v, pp2.x);
                                float N = fmaf(P, E, P + gev);
                                float Dd = fmaf(pp2.y, E, pp2.y + gw);
                                v = N * frcp(Dd);
                            }
                        }
                    }
                    gstate[gs] = v;
                } else {
                    float sv[CHK], nv[CHK];
#pragma unroll
                    for (int mm = 0; mm < CHK; ++mm) if (mm < gsz) sv[mm] = gstate[gs + mm];
                    for (int tt = 0; tt < TBS; ++tt) {
#pragma unroll
                        for (int u = 0; u < 6; ++u) {
#pragma unroll
                            for (int mm = 0; mm < CHK; ++mm)
                                if (mm < gsz && TL.need_traj[gs + mm])
                                    vtraj[(TL.traj_slot[gs + mm] * TBS + tt) * 7 + u] = sv[mm];
#pragma unroll
                            for (int mm = 0; mm < CHK; ++mm) {
                                if (mm < gsz) {
                                    int unit = TL.ord[gs + mm];
                                    float2 pp2 = pnpd[((m0 + mm) * TBS + tt) * 7 + u];
                                    float wn = pp2.x, wd = pp2.y;
                                    int ngpu = TL.ngp[unit];
#pragma unroll
                                    for (int e = 0; e < 6; ++e) {
                                        if (e < ngpu) {
                                            float vp = sv[TL.gp_pre[unit][e]];
                                            float gq = sgm(TL.gp_a[unit][e], TL.gp_b[unit][e], vp);
                                            wn = fmaf(TL.gp_e[unit][e], gq, wn);
                                            wd = fmaf(TL.gp_w[unit][e], gq, wd);
                                        }
                                    }
                                    nv[mm] = fmaf(TL.cmt[unit], sv[mm], wn) * frcp(wd);
                                }
                            }
#pragma unroll
                            for (int mm = 0; mm < CHK; ++mm) if (mm < gsz) sv[mm] = nv[mm];
                        }
                    }
#pragma unroll
                    for (int mm = 0; mm < CHK; ++mm) if (mm < gsz) gstate[gs + mm] = sv[mm];
                }
            }
            __syncthreads();
            for (int w = tid; w < npc * TBS; w += 512) {
                int m = w >> 7, tt = w & (TBS - 1);
                int posi = ps + m;
                if (TL.aff[posi] && TL.need_traj[posi]) {
                    int sl = TL.traj_slot[posi];
                    float v = vstart[m * TBS + tt];
#pragma unroll
                    for (int u = 0; u < 6; ++u) {
                        vtraj[(sl * TBS + tt) * 7 + u] = v;
                        float2 ab = pnpd[(m * TBS + tt) * 7 + u];
                        v = fmaf(ab.x, v, ab.y);
                    }
                }
            }
            __syncthreads();
        }
    }
    if (tid < 20 && tid < TL.npos) vstate[b * 32 + TL.ord[tid]] = gstate[tid];
    if (tid < 12) vstate[b * 32 + 20 + tid] = istate[tid];
    if (lastChunk) {
        __syncthreads();
        if (tid == 0) out[b] = fmaf(gstate[TL.pos[0]], ow[0], ob[0]);
    }
}

extern "C" void kernel_launch(void* const* d_in, const int* in_sizes, int n_in,
                              void* d_out, int out_size, void* d_ws, size_t ws_size,
                              hipStream_t stream) {
    fp x     = (fp)d_in[0];
    fp d1w   = (fp)d_in[1];
    fp d1b   = (fp)d_in[2];
    fp d2w   = (fp)d_in[3];
    fp d2b   = (fp)d_in[4];
    fp iw    = (fp)d_in[5];
    fp ib    = (fp)d_in[6];
    fp ow    = (fp)d_in[7];
    fp ob    = (fp)d_in[8];
    fp gleak = (fp)d_in[9];
    fp vleak = (fp)d_in[10];
    fp cm    = (fp)d_in[11];
    fp wsyn  = (fp)d_in[12];
    fp mu    = (fp)d_in[13];
    fp sigma = (fp)d_in[14];
    fp erev  = (fp)d_in[15];
    fp sw    = (fp)d_in[16];
    fp smu   = (fp)d_in[17];
    fp ssg   = (fp)d_in[18];
    fp serev = (fp)d_in[19];
    const int* spm   = (const int*)d_in[20];
    const int* smask = (const int*)d_in[21];

    char* wsb = (char*)d_ws;
    Tables*   T = (Tables*)wsb;
    DenseTab* D = (DenseTab*)(wsb + WS_DTAB);
    float*   bnd = (float*)(wsb + WS_BND);
    int*   bmask = (int*)(wsb + WS_BMASK);
    float2*   Mg = (float2*)(wsb + WS_MG);
    float* vstate = (float*)(wsb + WS_VST);
    float2* sensI = (float2*)(wsb + WS_SENSI);

    size_t per_t = (size_t)NB * 12 * sizeof(float2);     // 24576 B
    int CT = TBS;
    if (ws_size > WS_SENSI) {
        size_t m = (ws_size - WS_SENSI) / per_t;
        int ct = TBS;
        while (ct < NT && (size_t)(ct * 2) <= m) ct *= 2;
        CT = ct;
    }

    build_tables<<<1, 64, 0, stream>>>(wsyn, mu, sigma, erev, spm,
                                       sw, smu, ssg, serev, smask,
                                       cm, gleak, vleak, d1b, T, D);
    sector_prep<<<1, 256, 0, stream>>>(d1w, bnd, bmask);
    sector_M<<<256, 64, 0, stream>>>(d1w, d2w, iw, bmask, Mg);

    int nch = NT / CT;
    for (int c = 0; c < nch; ++c) {
        int t0 = c * CT;
        dense_general<<<512, 256, 0, stream>>>(x, d1w, d1b, d2w, d2b, iw, ib, D, sensI, t0, CT);
        solve<<<NB, 512, 0, stream>>>(x, sensI, T, D, Mg, bnd, d2b, iw, ib,
                                      ow, ob, vstate, t0, CT, (float*)d_out);
    }
}

// Round 21
// 248.865 us; speedup vs baseline: 2.1349x; 1.0006x over previous
//
#include <hip/hip_runtime.h>
#include <math.h>

#define NB 256
#define NT 1024
#define NUNF 6
#define TBS 128
#define CHK 8
#define NTJMAX 12
#define L2E 1.44269504088896340736f
#define PI_F 3.14159265358979324f

typedef const float* fp;

extern "C" __device__ float __ocml_exp2_f32(float);
__device__ __forceinline__ float frcp(float x) { return __builtin_amdgcn_rcpf(x); }
__device__ __forceinline__ float ex2(float x) { return __ocml_exp2_f32(x); }
__device__ __forceinline__ float sgm(float a, float b, float v) { return frcp(1.f + ex2(fmaf(a, v, b))); }

struct Tables {
    int ngroups, npos, nchunks, ntraj;
    int grp_start[21];
    int ord[20];
    int pos[20];
    int aff[20];
    int need_traj[20];
    int traj_slot[20];
    int ch_ps[20], ch_pe[20], ch_gs[20], ch_ge[20];
    int ncp[20], nip[20], ngp[20];
    float cmt[20], cn0[20], cd0[20];
    float icmt[12];
    int   cp_pre[20][8];          // traj SLOT of the pre unit
    float cp_a[20][8], cp_b[20][8], cp_w[20][8], cp_e[20][8];
    int   ip_i[20][12];
    float ip_a[20][12], ip_b[20][12], ip_w[20][12], ip_e[20][12];
    int   gp_pre[20][6];
    float gp_a[20][6], gp_b[20][6], gp_w[20][6], gp_e[20][6];
};

struct DenseTab {
    int cnt[12];
    float in0[12], id0[12];
    int   pre[12][32];
    float a[12][32], b[12][32], w[12][32], e[12][32];
    int homog, maxcnt;
};

// ws layout
#define WS_DTAB   16384
#define WS_BND    24576
#define WS_BMASK  25600
#define WS_MG     32768
#define WS_VST    98304
#define WS_SENSI  131072

// ---------------- K0: wiring analysis, lane-parallel in LDS ----------------
__global__ void build_tables(fp wsyn, fp mu, fp sigma, fp erev, const int* spm,
                             fp sw, fp smu, fp ssg, fp serev, const int* smask,
                             fp cm, fp gleak, fp vleak, fp d1b, Tables* T, DenseTab* D) {
    __shared__ int   spmL[1024], smkL[1024];
    __shared__ float wL[1024], muL[1024], sgL[1024], evL[1024];
    __shared__ float swL[1024], smuL[1024], ssgL[1024], sevL[1024];
    __shared__ float cmL[32], glL[32], vlL[32];
    __shared__ int premaskL[20], ancL[20], rootL[20], depUL[20], keyL[20], posL[20], ordL[20];
    __shared__ int ngpL[20], ntjL[20], slotU[20];
    __shared__ int neededS;
    __shared__ float habs[64];
    __shared__ int cntS[12];
    int tid = threadIdx.x;
    for (int k = tid; k < 1024; k += 64) {
        spmL[k] = spm[k]; wL[k] = wsyn[k]; muL[k] = mu[k]; sgL[k] = sigma[k]; evL[k] = erev[k];
        smkL[k] = smask[k]; swL[k] = sw[k]; smuL[k] = smu[k]; ssgL[k] = ssg[k]; sevL[k] = serev[k];
    }
    if (tid < 32) { cmL[tid] = cm[tid]; glL[tid] = gleak[tid]; vlL[tid] = vleak[tid]; }
    habs[tid] = fmaxf(fabsf(d1b[tid]), fabsf(d1b[tid + 64]));
    __syncthreads();
    if (tid < 20) {
        int pm = 0;
        for (int i = 0; i < 20; ++i) if (spmL[i * 32 + tid]) pm |= 1 << i;
        premaskL[tid] = pm;
        ancL[tid] = pm;
    }
    __syncthreads();
    for (int it = 0; it < 20; ++it) {
        int a = 0;
        if (tid < 20) {
            a = ancL[tid];
            int pm = premaskL[tid];
            for (int i = 0; i < 20; ++i) if ((pm >> i) & 1) a |= ancL[i];
        }
        __syncthreads();
        if (tid < 20) ancL[tid] = a;
        __syncthreads();
    }
    if (tid == 0) neededS = ancL[0] | 1;
    __syncthreads();
    int needed = neededS;
    if (tid < 20) {
        int r = tid;
        if ((needed >> tid) & 1) {
            int aj = ancL[tid];
            for (int i = 0; i < 20; ++i)
                if (i < r && ((needed >> i) & 1) && ((aj >> i) & 1) && ((ancL[i] >> tid) & 1)) r = i;
        }
        rootL[tid] = r;
        depUL[tid] = 0;
    }
    __syncthreads();
    for (int it = 0; it < 21; ++it) {
        int d = 0;
        if (tid < 20 && ((needed >> tid) & 1)) {
            int pm = premaskL[tid], myr = rootL[tid];
            for (int i = 0; i < 20; ++i)
                if (((pm >> i) & 1) && rootL[i] != myr) d = max(d, depUL[i] + 1);
        }
        __syncthreads();
        if (tid < 20 && d > depUL[tid]) depUL[tid] = d;
        __syncthreads();
    }
    if (tid < 20) {
        int key = 0x7FFFFFFF;
        if ((needed >> tid) & 1) {
            int myr = rootL[tid], dg = 0;
            for (int i = 0; i < 20; ++i)
                if (((needed >> i) & 1) && rootL[i] == myr) dg = max(dg, depUL[i]);
            key = dg * 32 + myr;
        }
        keyL[tid] = key;
    }
    __syncthreads();
    if (tid < 20) {
        int mykey = keyL[tid];
        int p = 0;
        for (int k = 0; k < 20; ++k)
            if (keyL[k] < mykey || (keyL[k] == mykey && k < tid)) ++p;
        posL[tid] = p;
        if (p < 20) ordL[p] = tid;
    }
    __syncthreads();
    if (tid < 20) {
        int nt = 0;
        if ((needed >> tid) & 1)
            for (int j = 0; j < 20; ++j)
                if (j != tid && ((needed >> j) & 1) && spmL[tid * 32 + j]) { nt = 1; break; }
        ntjL[tid] = nt;
    }
    __syncthreads();
    if (tid == 0) {
        int s = 0;
        for (int p = 0; p < 20; ++p) { int u = ordL[p]; slotU[u] = s; s += ntjL[u]; }
        T->ntraj = s;
    }
    __syncthreads();
    if (tid < 20) {
        int j = tid, cc = 0, ci = 0, cg = 0;
        T->cmt[j] = cmL[j] * (float)NUNF;
        T->cn0[j] = glL[j] * vlL[j];
        T->cd0[j] = cmL[j] * (float)NUNF + glL[j] + 1e-8f;
        if ((needed >> j) & 1) {
            int myr = rootL[j];
            int mystart = posL[myr];
            for (int i = 0; i < 32; ++i) {
                int p = i * 32 + j;
                if (!spmL[p]) continue;
                float sg = sgL[p];
                float a = -sg * L2E, b = sg * muL[p] * L2E;
                float w = wL[p], e = w * evL[p];
                if (i >= 20) {
                    T->ip_i[j][ci] = i - 20;
                    T->ip_a[j][ci] = a; T->ip_b[j][ci] = b; T->ip_w[j][ci] = w; T->ip_e[j][ci] = e;
                    ++ci;
                } else if (rootL[i] == myr) {
                    T->gp_pre[j][cg] = posL[i] - mystart;
                    T->gp_a[j][cg] = a; T->gp_b[j][cg] = b; T->gp_w[j][cg] = w; T->gp_e[j][cg] = e;
                    ++cg;
                } else {
                    T->cp_pre[j][cc] = slotU[i];
                    T->cp_a[j][cc] = a; T->cp_b[j][cc] = b; T->cp_w[j][cc] = w; T->cp_e[j][cc] = e;
                    ++cc;
                }
            }
        }
        T->ncp[j] = cc; T->nip[j] = ci; T->ngp[j] = cg;
        ngpL[j] = cg;
    }
    if (tid < 12) {
        T->icmt[tid] = cmL[20 + tid] * (float)NUNF;
        int unit = 20 + tid, cnt = 0;
        for (int s = 0; s < 32; ++s) {
            int p = s * 32 + unit;
            if (!smkL[p]) continue;
            float sg = ssgL[p];
            D->pre[tid][cnt] = s;
            D->a[tid][cnt] = -sg * L2E;
            D->b[tid][cnt] = sg * smuL[p] * L2E;
            D->w[tid][cnt] = swL[p];
            D->e[tid][cnt] = swL[p] * sevL[p];
            ++cnt;
        }
        for (int c = cnt; c < 32; ++c) {
            D->pre[tid][c] = 0; D->a[tid][c] = 0.f; D->b[tid][c] = 0.f;
            D->w[tid][c] = 0.f; D->e[tid][c] = 0.f;
        }
        D->cnt[tid] = cnt;
        cntS[tid] = cnt;
        D->in0[tid] = glL[unit] * vlL[unit];
        D->id0[tid] = cmL[unit] * (float)NUNF + glL[unit] + 1e-8f;
    }
    __syncthreads();
    if (tid == 0) {
        int npos = __popc(needed & 0xFFFFF);
        T->npos = npos;
        int ng = 0, prevkey = -1;
        for (int p = 0; p < npos; ++p) {
            int u = ordL[p];
            if (keyL[u] != prevkey) { T->grp_start[ng] = p; ++ng; prevkey = keyL[u]; }
        }
        T->ngroups = ng;
        for (int g = ng; g <= 20; ++g) T->grp_start[g] = npos;
        for (int p = 0; p < 20; ++p) T->ord[p] = (p < npos) ? ordL[p] : 0;
        for (int j = 0; j < 20; ++j) T->pos[j] = posL[j];
        for (int g = 0; g < ng; ++g) {
            int gs = T->grp_start[g], ge = T->grp_start[g + 1], gsz = ge - gs;
            for (int p = gs; p < ge; ++p)
                T->aff[p] = (gsz == 1 && ngpL[ordL[p]] == 0) ? 1 : 0;
        }
        for (int p = npos; p < 20; ++p) T->aff[p] = 0;
        for (int p = 0; p < 20; ++p) {
            int u = ordL[p];
            T->need_traj[p] = ntjL[u];
            T->traj_slot[p] = slotU[u];
        }
        int nchunks = 0, g = 0;
        while (g < ng) {
            int lvl = keyL[ordL[T->grp_start[g]]] / 32;
            int ge = g;
            while (ge < ng && keyL[ordL[T->grp_start[ge]]] / 32 == lvl) ++ge;
            int cs = g;
            while (cs < ge) {
                int ce = cs, acc = 0;
                while (ce < ge) {
                    int gsz = T->grp_start[ce + 1] - T->grp_start[ce];
                    if (acc + gsz > CHK && ce > cs) break;
                    acc += gsz; ++ce;
                    if (acc >= CHK) break;
                }
                T->ch_gs[nchunks] = cs; T->ch_ge[nchunks] = ce;
                T->ch_ps[nchunks] = T->grp_start[cs]; T->ch_pe[nchunks] = T->grp_start[ce];
                ++nchunks;
                cs = ce;
            }
            g = ge;
        }
        T->nchunks = nchunks;
        float hm = 0.f;
        for (int k = 0; k < 64; ++k) hm = fmaxf(hm, habs[k]);
        D->homog = (hm == 0.f) ? 1 : 0;
        int mc = 0;
        for (int k = 0; k < 12; ++k) mc = max(mc, cntS[k]);
        D->maxcnt = mc;
    }
}

// ---------------- K0b: boundary angles of the 128 origin-lines, sorted (1 block) ----------------
__global__ void sector_prep(fp d1w, float* bnd, int* bmask) {
    __shared__ float ang[256];
    __shared__ float uS[128], vS[128];
    int tid = threadIdx.x;
    if (tid < 128) { uS[tid] = d1w[tid]; vS[tid] = d1w[128 + tid]; }
    __syncthreads();
    {
        int k = tid & 127;
        float al = atan2f(vS[k], uS[k]);
        float bb = (tid < 128) ? al + 1.57079632679489662f : al - 1.57079632679489662f;
        if (bb > PI_F) bb -= 2.f * PI_F;
        if (bb <= -PI_F) bb += 2.f * PI_F;
        ang[tid] = bb;
    }
    __syncthreads();
    for (int k = 2; k <= 256; k <<= 1) {
        for (int j = k >> 1; j > 0; j >>= 1) {
            int ixj = tid ^ j;
            if (ixj > tid) {
                float a0 = ang[tid], a1 = ang[ixj];
                bool up = ((tid & k) == 0);
                if ((a0 > a1) == up) { ang[tid] = a1; ang[ixj] = a0; }
            }
            __syncthreads();
        }
    }
    bnd[tid] = ang[tid];
    float lo = ang[tid];
    float hi = (tid < 255) ? ang[tid + 1] : ang[0] + 2.f * PI_F;
    float tm = 0.5f * (lo + hi);
    float ct = cosf(tm), st = sinf(tm);
    for (int w = 0; w < 4; ++w) {
        int m = 0;
        for (int kk = 0; kk < 32; ++kk) {
            int k = w * 32 + kk;
            if (fmaf(uS[k], ct, vS[k] * st) > 0.f) m |= 1 << kk;
        }
        bmask[tid * 4 + w] = m;
    }
}

// ---------------- K0c: per-sector collapsed 2x32 dense map (256 blocks) ----------------
__global__ void sector_M(fp d1w, fp d2w, fp iw, const int* bmask, float2* Mg) {
    int s = blockIdx.x, j = threadIdx.x;
    if (j >= 32) return;
    float acc0 = 0.f, acc1 = 0.f;
#pragma unroll
    for (int w = 0; w < 4; ++w) {
        int mm = bmask[s * 4 + w];
        for (int kk = 0; kk < 32; ++kk) {
            if ((mm >> kk) & 1) {
                int k = w * 32 + kk;
                float w2 = d2w[k * 32 + j];
                acc0 = fmaf(d1w[k], w2, acc0);
                acc1 = fmaf(d1w[128 + k], w2, acc1);
            }
        }
    }
    float iwj = iw[j];
    Mg[s * 32 + j] = make_float2(acc0 * iwj, acc1 * iwj);
}

// ---------------- K1b: general fallback dense; early-exits when homog ----------------
__global__ __launch_bounds__(256) void dense_general(
    fp x, fp d1w, fp d1b, fp d2w, fp d2b, fp iw, fp ib,
    const DenseTab* __restrict__ Dg, float2* sensI, int t0, int CT) {
    if (Dg->homog != 0) return;
    __shared__ float W2s[4096];
    __shared__ float W1s[256], b1s[128];
    __shared__ float b2q[32], iwq[32], ibq[32];
    __shared__ float4 tabT[416];
    __shared__ int   preT[416];
    __shared__ int   cntL[12];
    __shared__ float in0L[12], id0L[12];
    __shared__ float hbuf[4][128][20];
    __shared__ float ibuf[4][16][33];
    int tid = threadIdx.x;
    for (int idx = tid; idx < 384; idx += 256) {
        int d = idx >> 5, e = idx & 31;
        int sl = e * 13 + d;
        tabT[sl] = make_float4(Dg->a[d][e], Dg->b[d][e], Dg->w[d][e], Dg->e[d][e]);
        preT[sl] = Dg->pre[d][e];
    }
    if (tid < 12) { cntL[tid] = Dg->cnt[tid]; in0L[tid] = Dg->in0[tid]; id0L[tid] = Dg->id0[tid]; }
    for (int p = tid; p < 4096; p += 256) W2s[p] = d2w[p];
    if (tid < 256) W1s[tid] = d1w[tid];
    if (tid < 128) b1s[tid] = d1b[tid];
    if (tid < 32) { b2q[tid] = d2b[tid]; iwq[tid] = iw[tid]; ibq[tid] = ib[tid]; }
    __syncthreads();
    int wid = tid >> 6, lane = tid & 63;
    float* hb = (float*)hbuf[wid];
    float* ibf = (float*)ibuf[wid];
    const float2* x2 = (const float2*)x;
    int gw = blockIdx.x * 4 + wid;
    int nw = gridDim.x * 4;
    int pass_total = (NB * CT) >> 4;
    int itd1 = lane >> 2, kq = lane & 3;
    int j = lane & 31, half = lane >> 5;
    for (int pass = gw; pass < pass_total; pass += nw) {
        int cg0 = pass * 16;
        {
            int cg = cg0 + itd1;
            int lt = cg >> 8, b = cg & 255;
            float2 xv = x2[b * NT + (t0 + lt)];
#pragma unroll 8
            for (int i = 0; i < 32; ++i) {
                int k = kq + 4 * i;
                float hk = fmaf(xv.y, W1s[128 + k], fmaf(xv.x, W1s[k], b1s[k]));
                hb[k * 20 + itd1] = hk > 0.f ? hk : 0.f;
            }
        }
        __builtin_amdgcn_wave_barrier();
        {
            float a0=0,a1=0,a2=0,a3=0,a4=0,a5=0,a6=0,a7=0;
#pragma unroll 4
            for (int k = 0; k < 128; ++k) {
                float w2 = W2s[k * 32 + j];
                float4 ha = *(const float4*)&hb[k * 20 + half * 8];
                float4 hbv = *(const float4*)&hb[k * 20 + half * 8 + 4];
                a0 = fmaf(ha.x, w2, a0); a1 = fmaf(ha.y, w2, a1);
                a2 = fmaf(ha.z, w2, a2); a3 = fmaf(ha.w, w2, a3);
                a4 = fmaf(hbv.x, w2, a4); a5 = fmaf(hbv.y, w2, a5);
                a6 = fmaf(hbv.z, w2, a6); a7 = fmaf(hbv.w, w2, a7);
            }
            float bb = b2q[j], iww = iwq[j], ibb = ibq[j];
            ibf[(half*8+0)*33+j] = fmaf(a0+bb, iww, ibb);
            ibf[(half*8+1)*33+j] = fmaf(a1+bb, iww, ibb);
            ibf[(half*8+2)*33+j] = fmaf(a2+bb, iww, ibb);
            ibf[(half*8+3)*33+j] = fmaf(a3+bb, iww, ibb);
            ibf[(half*8+4)*33+j] = fmaf(a4+bb, iww, ibb);
            ibf[(half*8+5)*33+j] = fmaf(a5+bb, iww, ibb);
            ibf[(half*8+6)*33+j] = fmaf(a6+bb, iww, ibb);
            ibf[(half*8+7)*33+j] = fmaf(a7+bb, iww, ibb);
        }
        __builtin_amdgcn_wave_barrier();
#pragma unroll
        for (int r = 0; r < 3; ++r) {
            int task = r * 64 + lane;
            int it = task / 12;
            int d = task - it * 12;
            int cnt = cntL[d];
            float wn = in0L[d], wd = id0L[d];
            for (int e = 0; e < cnt; ++e) {
                int sl = e * 13 + d;
                float4 tb = tabT[sl];
                float gq = frcp(1.f + ex2(fmaf(tb.x, ibf[it * 33 + preT[sl]], tb.y)));
                wn = fmaf(tb.w, gq, wn);
                wd = fmaf(tb.z, gq, wd);
            }
            int cg = cg0 + it;
            int lt = cg >> 8, b = cg & 255;
            sensI[(size_t)(b * CT + lt) * 12 + d] = make_float2(wn, wd);
        }
        __builtin_amdgcn_wave_barrier();
    }
}

// ---------------- K2: fused solver; serial scans use register prefetch of pnpd/iAB ----------------
__global__ __launch_bounds__(512) void solve(
    fp x, const float2* __restrict__ sensI,
    const Tables* __restrict__ Tg, const DenseTab* __restrict__ Dg,
    const float2* __restrict__ Mg, const float* __restrict__ bndg,
    fp d2b, fp iw, fp ib,
    fp ow, fp ob, float* vstate, int t0, int CT, float* out) {
    __shared__ Tables TL;
    __shared__ float2 iAB[TBS * 12];
    __shared__ float viter[TBS * 13];
    __shared__ float vtraj[NTJMAX * TBS * 7];
    __shared__ float2 pnpd[CHK * TBS * 7];       // aliased as inp scratch during dense phase
    __shared__ float2 comp[CHK * TBS];
    __shared__ float vstart[CHK * TBS];
    __shared__ float gstate[20], istate[12];
    __shared__ float bndL[256];
    __shared__ float4 tabT[416];
    __shared__ int   preT[416];
    __shared__ float cjL[32];
    __shared__ float in0L[12], id0L[12];
    __shared__ int   secS[128];
    __shared__ float x0S[128], x1S[128];
    int tid = threadIdx.x;
    int b = blockIdx.x;
    {
        const int nw = (int)(sizeof(Tables) / 4);
        const int* src = (const int*)Tg;
        int* dst = (int*)&TL;
        for (int k = tid; k < nw; k += 512) dst[k] = src[k];
    }
    int homog = Dg->homog;
    int cntmax = Dg->maxcnt;
    if (homog) {
        for (int idx = tid; idx < 384; idx += 512) {
            int d = idx >> 5, e = idx & 31;
            int sl = e * 13 + d;
            tabT[sl] = make_float4(Dg->a[d][e], Dg->b[d][e], Dg->w[d][e], Dg->e[d][e]);
            preT[sl] = Dg->pre[d][e];
        }
        if (tid < 256) bndL[tid] = bndg[tid];
        if (tid < 32) cjL[tid] = fmaf(d2b[tid], iw[tid], ib[tid]);
        if (tid < 12) { in0L[tid] = Dg->in0[tid]; id0L[tid] = Dg->id0[tid]; }
    }
    __syncthreads();
    if (tid < 20 && tid < TL.npos)
        gstate[tid] = (t0 == 0) ? 0.f : vstate[b * 32 + TL.ord[tid]];
    if (tid < 12)
        istate[tid] = (t0 == 0) ? 0.f : vstate[b * 32 + 20 + tid];
    __syncthreads();
    int ntiles = CT / TBS;
    bool lastChunk = (t0 + CT == NT);
    const float2* x2 = (const float2*)x;
    int nchunks = TL.nchunks;
    for (int tile = 0; tile < ntiles; ++tile) {
        int tbase = tile * TBS;
        if (homog) {
            // ---- phase 1: sector + x per item (128 lanes) ----
            if (tid < 128) {
                float2 xv = x2[(size_t)b * NT + (t0 + tbase + tid)];
                x0S[tid] = xv.x; x1S[tid] = xv.y;
                float th = atan2f(xv.y, xv.x);
                int sec;
                if (th < bndL[0]) sec = 255;
                else {
                    int lo = 0, hi = 255;
#pragma unroll
                    for (int it7 = 0; it7 < 8; ++it7) {
                        int mid = (lo + hi + 1) >> 1;
                        if (bndL[mid] <= th) lo = mid; else hi = mid - 1;
                    }
                    sec = lo;
                }
                secS[tid] = sec;
            }
            __syncthreads();
            // ---- phase 2: inp via coalesced Mg reads (j lane-consecutive) ----
            float* ibufL = (float*)pnpd;
            {
                int j = tid & 31, grp = tid >> 5;   // 16 groups x 8 items
                float cj = cjL[j];
#pragma unroll
                for (int c = 0; c < 8; ++c) {
                    int item = grp * 8 + c;
                    float2 m = Mg[secS[item] * 32 + j];
                    ibufL[item * 33 + j] = fmaf(x0S[item], m.x, fmaf(x1S[item], m.y, cj));
                }
            }
            __syncthreads();
            // ---- phase 3: gate sums -> iAB (1536 tasks, 3 rounds) ----
#pragma unroll
            for (int rb = 0; rb < 3; ++rb) {
                int task = rb * 512 + tid;
                int item = task / 12;
                int dd = task - item * 12;
                float wn = in0L[dd], wd = id0L[dd];
                for (int e = 0; e < cntmax; ++e) {
                    int sl = e * 13 + dd;
                    float4 tb = tabT[sl];
                    float gq = frcp(1.f + ex2(fmaf(tb.x, ibufL[item * 33 + preT[sl]], tb.y)));
                    wn = fmaf(tb.w, gq, wn);
                    wd = fmaf(tb.z, gq, wd);
                }
                float r = frcp(wd);
                iAB[item * 12 + dd] = make_float2(TL.icmt[dd] * r, wn * r);
            }
        } else {
            for (int w = tid; w < TBS * 16; w += 512) {
                int tt = w >> 4, ii = w & 15;
                if (ii < 12) {
                    float2 s = sensI[(size_t)(b * CT + tbase + tt) * 12 + ii];
                    float r = frcp(s.y);
                    iAB[tt * 12 + ii] = make_float2(TL.icmt[ii] * r, s.x * r);
                }
            }
        }
        __syncthreads();
        // ---- inter scan with iAB register prefetch ----
        if (tid < 12) {
            float v = istate[tid];
            float2 ab = iAB[tid];
            for (int tt = 0; tt < TBS; ++tt) {
                int tn = (tt + 1 < TBS) ? (tt + 1) : tt;
                float2 abn = iAB[tn * 12 + tid];
                float A = ab.x, B = ab.y;
                float A2 = A * A, A4 = A2 * A2;
                float A6 = A4 * A2;
                float B6 = B * (1.f + A) * (1.f + A2 + A4);
                viter[tt * 13 + tid] = v;
                v = fmaf(A6, v, B6);
                ab = abn;
            }
            istate[tid] = v;
        }
        __syncthreads();
        for (int c = 0; c < nchunks; ++c) {
            int ps = TL.ch_ps[c], pe = TL.ch_pe[c];
            int gs0 = TL.ch_gs[c], ge0 = TL.ch_ge[c];
            int npc = pe - ps;
            for (int w = tid; w < npc * TBS; w += 512) {
                int m = w >> 7, tt = w & (TBS - 1);
                int posi = ps + m;
                int unit = TL.ord[posi];
                float pn[6], pd[6];
#pragma unroll
                for (int u = 0; u < 6; ++u) { pn[u] = TL.cn0[unit]; pd[u] = TL.cd0[unit]; }
                int ncp = TL.ncp[unit];
                for (int e = 0; e < ncp; ++e) {
                    int sl = TL.cp_pre[unit][e];
                    float a = TL.cp_a[unit][e], bb = TL.cp_b[unit][e];
                    float w_ = TL.cp_w[unit][e], ev = TL.cp_e[unit][e];
#pragma unroll
                    for (int u = 0; u < 6; ++u) {
                        float gq = sgm(a, bb, vtraj[(sl * TBS + tt) * 7 + u]);
                        pn[u] = fmaf(ev, gq, pn[u]);
                        pd[u] = fmaf(w_, gq, pd[u]);
                    }
                }
                int nip = TL.nip[unit];
                for (int e = 0; e < nip; ++e) {
                    int ii = TL.ip_i[unit][e];
                    float2 ab = iAB[tt * 12 + ii];
                    float vi = viter[tt * 13 + ii];
                    float a = TL.ip_a[unit][e], bb = TL.ip_b[unit][e];
                    float w_ = TL.ip_w[unit][e], ev = TL.ip_e[unit][e];
#pragma unroll
                    for (int u = 0; u < 6; ++u) {
                        float gq = sgm(a, bb, vi);
                        pn[u] = fmaf(ev, gq, pn[u]);
                        pd[u] = fmaf(w_, gq, pd[u]);
                        vi = fmaf(ab.x, vi, ab.y);
                    }
                }
                if (TL.aff[posi]) {
                    float cmt = TL.cmt[unit];
                    float Ac = 1.f, Bc = 0.f;
#pragma unroll
                    for (int u = 0; u < 6; ++u) {
                        float r = frcp(pd[u]);
                        float Au = cmt * r, Bu = pn[u] * r;
                        pnpd[(m * TBS + tt) * 7 + u] = make_float2(Au, Bu);
                        Bc = fmaf(Au, Bc, Bu);
                        Ac *= Au;
                    }
                    comp[m * TBS + tt] = make_float2(Ac, Bc);
                } else {
#pragma unroll
                    for (int u = 0; u < 6; ++u)
                        pnpd[(m * TBS + tt) * 7 + u] = make_float2(pn[u], pd[u]);
                }
            }
            __syncthreads();
            if (tid < ge0 - gs0) {
                int g = gs0 + tid;
                int gs = TL.grp_start[g], ge = TL.grp_start[g + 1], gsz = ge - gs;
                int m0 = gs - ps;
                if (gsz == 1) {
                    int unit = TL.ord[gs];
                    float v = gstate[gs];
                    if (TL.aff[gs]) {
                        float2 cc = comp[m0 * TBS];
                        for (int tt = 0; tt < TBS; ++tt) {
                            int tn = (tt + 1 < TBS) ? (tt + 1) : tt;
                            float2 cn = comp[m0 * TBS + tn];
                            vstart[m0 * TBS + tt] = v;
                            v = fmaf(cc.x, v, cc.y);
                            cc = cn;
                        }
                    } else {
                        // self-loop singleton: rational form + pnpd register prefetch
                        float ga = TL.gp_a[unit][0], gb = TL.gp_b[unit][0];
                        float gw = TL.gp_w[unit][0], gev = TL.gp_e[unit][0];
                        float cmt = TL.cmt[unit];
                        int ntj = TL.need_traj[gs];
                        int sl = TL.traj_slot[gs];
                        __builtin_amdgcn_s_setprio(1);
                        const float2* pb0 = &pnpd[(m0 * TBS) * 7];
                        float2 c0 = pb0[0], c1 = pb0[1], c2 = pb0[2];
                        float2 c3 = pb0[3], c4 = pb0[4], c5 = pb0[5];
                        for (int tt = 0; tt < TBS; ++tt) {
                            int tn = (tt + 1 < TBS) ? (tt + 1) : tt;
                            const float2* pbn = &pnpd[(m0 * TBS + tn) * 7];
                            float2 n0 = pbn[0], n1 = pbn[1], n2 = pbn[2];
                            float2 n3 = pbn[3], n4 = pbn[4], n5 = pbn[5];
                            float* vt = &vtraj[(sl * TBS + tt) * 7];
#define CSTEP(cc, uu) { if (ntj) vt[uu] = v; \
                            float E = ex2(fmaf(ga, v, gb)); \
                            float P = fmaf(cmt, v, cc.x); \
                            float N = fmaf(P, E, P + gev); \
                            float Dd = fmaf(cc.y, E, cc.y + gw); \
                            v = N * frcp(Dd); }
                            CSTEP(c0, 0) CSTEP(c1, 1) CSTEP(c2, 2)
                            CSTEP(c3, 3) CSTEP(c4, 4) CSTEP(c5, 5)
#undef CSTEP
                            c0 = n0; c1 = n1; c2 = n2; c3 = n3; c4 = n4; c5 = n5;
                        }
                        __builtin_amdgcn_s_setprio(0);
                    }
                    gstate[gs] = v;
                } else {
                    float sv[CHK], nv[CHK];
#pragma unroll
                    for (int mm = 0; mm < CHK; ++mm) if (mm < gsz) sv[mm] = gstate[gs + mm];
                    for (int tt = 0; tt < TBS; ++tt) {
#pragma unroll
                        for (int u = 0; u < 6; ++u) {
#pragma unroll
                            for (int mm = 0; mm < CHK; ++mm)
                                if (mm < gsz && TL.need_traj[gs + mm])
                                    vtraj[(TL.traj_slot[gs + mm] * TBS + tt) * 7 + u] = sv[mm];
#pragma unroll
                            for (int mm = 0; mm < CHK; ++mm) {
                                if (mm < gsz) {
                                    int unit = TL.ord[gs + mm];
                                    float2 pp2 = pnpd[((m0 + mm) * TBS + tt) * 7 + u];
                                    float wn = pp2.x, wd = pp2.y;
                                    int ngpu = TL.ngp[unit];
#pragma unroll
                                    for (int e = 0; e < 6; ++e) {
                                        if (e < ngpu) {
                                            float vp = sv[TL.gp_pre[unit][e]];
                                            float gq = sgm(TL.gp_a[unit][e], TL.gp_b[unit][e], vp);
                                            wn = fmaf(TL.gp_e[unit][e], gq, wn);
                                            wd = fmaf(TL.gp_w[unit][e], gq, wd);
                                        }
                                    }
                                    nv[mm] = fmaf(TL.cmt[unit], sv[mm], wn) * frcp(wd);
                                }
                            }
#pragma unroll
                            for (int mm = 0; mm < CHK; ++mm) if (mm < gsz) sv[mm] = nv[mm];
                        }
                    }
#pragma unroll
                    for (int mm = 0; mm < CHK; ++mm) if (mm < gsz) gstate[gs + mm] = sv[mm];
                }
            }
            __syncthreads();
            for (int w = tid; w < npc * TBS; w += 512) {
                int m = w >> 7, tt = w & (TBS - 1);
                int posi = ps + m;
                if (TL.aff[posi] && TL.need_traj[posi]) {
                    int sl = TL.traj_slot[posi];
                    float v = vstart[m * TBS + tt];
#pragma unroll
                    for (int u = 0; u < 6; ++u) {
                        vtraj[(sl * TBS + tt) * 7 + u] = v;
                        float2 ab = pnpd[(m * TBS + tt) * 7 + u];
                        v = fmaf(ab.x, v, ab.y);
                    }
                }
            }
            __syncthreads();
        }
    }
    if (tid < 20 && tid < TL.npos) vstate[b * 32 + TL.ord[tid]] = gstate[tid];
    if (tid < 12) vstate[b * 32 + 20 + tid] = istate[tid];
    if (lastChunk) {
        __syncthreads();
        if (tid == 0) out[b] = fmaf(gstate[TL.pos[0]], ow[0], ob[0]);
    }
}

extern "C" void kernel_launch(void* const* d_in, const int* in_sizes, int n_in,
                              void* d_out, int out_size, void* d_ws, size_t ws_size,
                              hipStream_t stream) {
    fp x     = (fp)d_in[0];
    fp d1w   = (fp)d_in[1];
    fp d1b   = (fp)d_in[2];
    fp d2w   = (fp)d_in[3];
    fp d2b   = (fp)d_in[4];
    fp iw    = (fp)d_in[5];
    fp ib    = (fp)d_in[6];
    fp ow    = (fp)d_in[7];
    fp ob    = (fp)d_in[8];
    fp gleak = (fp)d_in[9];
    fp vleak = (fp)d_in[10];
    fp cm    = (fp)d_in[11];
    fp wsyn  = (fp)d_in[12];
    fp mu    = (fp)d_in[13];
    fp sigma = (fp)d_in[14];
    fp erev  = (fp)d_in[15];
    fp sw    = (fp)d_in[16];
    fp smu   = (fp)d_in[17];
    fp ssg   = (fp)d_in[18];
    fp serev = (fp)d_in[19];
    const int* spm   = (const int*)d_in[20];
    const int* smask = (const int*)d_in[21];

    char* wsb = (char*)d_ws;
    Tables*   T = (Tables*)wsb;
    DenseTab* D = (DenseTab*)(wsb + WS_DTAB);
    float*   bnd = (float*)(wsb + WS_BND);
    int*   bmask = (int*)(wsb + WS_BMASK);
    float2*   Mg = (float2*)(wsb + WS_MG);
    float* vstate = (float*)(wsb + WS_VST);
    float2* sensI = (float2*)(wsb + WS_SENSI);

    size_t per_t = (size_t)NB * 12 * sizeof(float2);     // 24576 B
    int CT = TBS;
    if (ws_size > WS_SENSI) {
        size_t m = (ws_size - WS_SENSI) / per_t;
        int ct = TBS;
        while (ct < NT && (size_t)(ct * 2) <= m) ct *= 2;
        CT = ct;
    }

    build_tables<<<1, 64, 0, stream>>>(wsyn, mu, sigma, erev, spm,
                                       sw, smu, ssg, serev, smask,
                                       cm, gleak, vleak, d1b, T, D);
    sector_prep<<<1, 256, 0, stream>>>(d1w, bnd, bmask);
    sector_M<<<256, 64, 0, stream>>>(d1w, d2w, iw, bmask, Mg);

    int nch = NT / CT;
    for (int c = 0; c < nch; ++c) {
        int t0 = c * CT;
        dense_general<<<512, 256, 0, stream>>>(x, d1w, d1b, d2w, d2b, iw, ib, D, sensI, t0, CT);
        solve<<<NB, 512, 0, stream>>>(x, sensI, T, D, Mg, bnd, d2b, iw, ib,
                                      ow, ob, vstate, t0, CT, (float*)d_out);
    }
}